// Round 10
// baseline (510.958 us; speedup 1.0000x reference)
//
#include <hip/hip_runtime.h>
#include <hip/hip_fp8.h>
#include <math.h>

#define NN 3072
#define NU 1024
#define NI 2048
#define DD 128
#define BB 8192
#define GAMMA_F 0.2f

#define SCALE_A 524288.0f                // 2^19
#define F8SCALE2 1.9073486328125e-06f    // 2^-19  (C*2^38 -> A2*2^19 for fp8)
#define DESCALE38 3.637978807091713e-12f // 2^-38  (C -> true A^k values)

typedef __attribute__((ext_vector_type(4))) float f32x4;

// async global->LDS, 16B per lane; LDS dst = wave-uniform base + lane*16
#define GLDS16(g, l)                                                          \
  __builtin_amdgcn_global_load_lds(                                           \
      (__attribute__((address_space(1))) void*)(g),                           \
      (__attribute__((address_space(3))) void*)(l), 16, 0, 0)

static __device__ inline unsigned short bf16bits(float x) {
  union { unsigned u; float f; } cv;
  cv.f = x;
  unsigned r = cv.u + 0x7fff + ((cv.u >> 16) & 1);  // RNE
  return (unsigned short)(r >> 16);
}

// pack 4 floats -> 4 fp8 e4m3 (OCP) bytes
static __device__ inline unsigned pk4_f8(float a, float b, float c, float d) {
#if defined(__has_builtin)
#if __has_builtin(__builtin_amdgcn_cvt_pk_fp8_f32)
  int p = __builtin_amdgcn_cvt_pk_fp8_f32(a, b, 0, false);
  p = __builtin_amdgcn_cvt_pk_fp8_f32(c, d, p, true);
  return (unsigned)p;
#else
  return (unsigned)__hip_fp8_e4m3(a).__x | ((unsigned)__hip_fp8_e4m3(b).__x << 8) |
         ((unsigned)__hip_fp8_e4m3(c).__x << 16) |
         ((unsigned)__hip_fp8_e4m3(d).__x << 24);
#endif
#else
  return (unsigned)__hip_fp8_e4m3(a).__x | ((unsigned)__hip_fp8_e4m3(b).__x << 8) |
         ((unsigned)__hip_fp8_e4m3(c).__x << 16) |
         ((unsigned)__hip_fp8_e4m3(d).__x << 24);
#endif
}

// fast fp32 global atomic add (tiny y1/s1 accumulators only)
static __device__ inline void atomAddF(float* p, float v) {
#if defined(__has_builtin)
#if __has_builtin(__builtin_amdgcn_global_atomic_fadd_f32)
  __builtin_amdgcn_global_atomic_fadd_f32(
      (__attribute__((address_space(1))) float*)p, v);
#else
  unsafeAtomicAdd(p, v);
#endif
#else
  unsafeAtomicAdd(p, v);
#endif
}

static __device__ inline float block_sum(float s, float* red4) {
  int tid = threadIdx.x;
  for (int off = 32; off; off >>= 1) s += __shfl_down(s, off, 64);
  if ((tid & 63) == 0) red4[tid >> 6] = s;
  __syncthreads();
  return red4[0] + red4[1] + red4[2] + red4[3];
}

static __device__ inline float row_dot_f32(const float* __restrict__ a,
                                           const float* __restrict__ b,
                                           float* red4) {
  const float4* ap = (const float4*)a;
  const float4* bp = (const float4*)b;
  float s = 0.f;
  for (int j = threadIdx.x; j < NN / 4; j += 256) {
    float4 x = ap[j], y = bp[j];
    s += x.x * y.x + x.y * y.y + x.z * y.z + x.w * y.w;
  }
  return block_sum(s, red4);
}

// ---------------------------------------------------------------------------
// Per-row top-64 via radix select on bits [30..16] with wave OR/AND
// prefix-skip; one wave per row; keys compared as f's own bits.
// bf=1: base = bf16 partials (parts buffers). bf=0: fp32 matrix.
static __device__ void topk_row_dev(const void* __restrict__ base, int parts,
                                    int bf, int row, int lane, float descale,
                                    int* __restrict__ outCnt,
                                    int* __restrict__ outIdx,
                                    float* __restrict__ outVal,
                                    unsigned char* __restrict__ outF8,
                                    float f8scale) {
  float f[48];
  if (bf) {
    const unsigned short* b0 = (const unsigned short*)base;
    const uint4* r0 = (const uint4*)(b0 + (size_t)row * NN);
#pragma unroll
    for (int j = 0; j < 6; ++j) {
      uint4 q = r0[lane + j * 64];
      unsigned uu[4] = {q.x, q.y, q.z, q.w};
#pragma unroll
      for (int e = 0; e < 4; ++e) {
        f[j * 8 + e * 2] = __uint_as_float(uu[e] << 16);
        f[j * 8 + e * 2 + 1] = __uint_as_float(uu[e] & 0xffff0000u);
      }
    }
    for (int p = 1; p < parts; ++p) {
      const uint4* rp =
          (const uint4*)(b0 + (size_t)p * NN * NN + (size_t)row * NN);
#pragma unroll
      for (int j = 0; j < 6; ++j) {
        uint4 q = rp[lane + j * 64];
        unsigned uu[4] = {q.x, q.y, q.z, q.w};
#pragma unroll
        for (int e = 0; e < 4; ++e) {
          f[j * 8 + e * 2] += __uint_as_float(uu[e] << 16);
          f[j * 8 + e * 2 + 1] += __uint_as_float(uu[e] & 0xffff0000u);
        }
      }
    }
  } else {
    const float4* r0 = (const float4*)((const float*)base + (size_t)row * NN);
#pragma unroll
    for (int j = 0; j < 12; ++j) {
      float4 a = r0[lane + j * 64];
      f[j * 4 + 0] = a.x; f[j * 4 + 1] = a.y;
      f[j * 4 + 2] = a.z; f[j * 4 + 3] = a.w;
    }
  }
  if (outF8) {
    // bf path layout: f[j*8+e] = col (j*64+lane)*8 + e
    uint2* ob = (uint2*)(outF8 + (size_t)row * NN);
#pragma unroll
    for (int j = 0; j < 6; ++j) {
      uint2 w;
      w.x = pk4_f8(f[j * 8 + 0] * f8scale, f[j * 8 + 1] * f8scale,
                   f[j * 8 + 2] * f8scale, f[j * 8 + 3] * f8scale);
      w.y = pk4_f8(f[j * 8 + 4] * f8scale, f[j * 8 + 5] * f8scale,
                   f[j * 8 + 6] * f8scale, f[j * 8 + 7] * f8scale);
      ob[lane + j * 64] = w;
    }
  }
  // wave-wide OR / AND of keys -> constant-prefix skip
  unsigned bor = 0, band = 0xffffffffu;
#pragma unroll
  for (int r = 0; r < 48; ++r) {
    unsigned k = __float_as_uint(f[r]);
    bor |= k; band &= k;
  }
  for (int off = 32; off; off >>= 1) {
    bor |= (unsigned)__shfl_down((int)bor, off, 64);
    band &= (unsigned)__shfl_down((int)band, off, 64);
  }
  bor = (unsigned)__shfl((int)bor, 0, 64);
  band = (unsigned)__shfl((int)band, 0, 64);
  unsigned diff = bor ^ band;
  int hi = diff ? (31 - __clz(diff)) : 16;
  if (hi < 16) hi = 16;
  if (hi > 30) hi = 30;
  unsigned t = band & ~((hi < 31) ? ((2u << hi) - 1u) : 0xffffffffu);

  for (int b = hi; b >= 16; --b) {
    unsigned cand = t | (1u << b);
    int c = 0;
#pragma unroll
    for (int r = 0; r < 48; ++r) c += (__float_as_uint(f[r]) >= cand) ? 1 : 0;
    for (int off = 32; off; off >>= 1) c += __shfl_down(c, off, 64);
    c = __shfl(c, 0, 64);
    if (c >= 64) t = cand;
  }
  int basec = 0;
  int* oi = outIdx + (size_t)row * 128;
  float* ov = outVal + (size_t)row * 128;
#pragma unroll
  for (int r = 0; r < 48; ++r) {
    bool keep = __float_as_uint(f[r]) >= t;
    unsigned long long m = __ballot(keep);
    if (keep) {
      int pos = basec + __popcll(m & ((1ull << lane) - 1ull));
      if (pos < 128) {
        oi[pos] = bf ? ((r >> 3) * 512 + lane * 8 + (r & 7))
                     : ((r >> 2) * 256 + lane * 4 + (r & 3));
        ov[pos] = f[r] * descale;
      }
    }
    basec += __popcll(m);
  }
  if (lane == 0) outCnt[row] = basec < 128 ? basec : 128;
}

// ---------------------------------------------------------------------------
// fp8 GEMM tile body: C(128x128, bf16) = A * Bt, BK=64; split-K part z.
static __device__ void gemm_f8_body(const unsigned char* __restrict__ Ag,
                                    const unsigned char* __restrict__ Btg,
                                    unsigned short* __restrict__ Cg, int kLen,
                                    int bx, int by, int z) {
  __shared__ __align__(16) unsigned char As[8192];
  __shared__ __align__(16) unsigned char Bs[8192];

  const int tid = threadIdx.x;
  const int wave = tid >> 6;
  const int lane = tid & 63;
  const int rowBase = by * 128;
  const int colBase = bx * 128;
  const int wr = wave >> 1, wc = wave & 1;
  const int lrow = lane & 15, lq = lane >> 4;
  const int kStart = z * kLen;
  unsigned short* Cout = Cg + (size_t)z * NN * NN;

  f32x4 acc[4][4];
  for (int i = 0; i < 4; ++i)
    for (int j = 0; j < 4; ++j) acc[i][j] = (f32x4){0.f, 0.f, 0.f, 0.f};

  const unsigned char* aS0 =
      Ag + (size_t)(rowBase + 2 * wave * 16 + lrow) * NN + lq * 16;
  const unsigned char* aS1 = aS0 + (size_t)16 * NN;
  const unsigned char* bS0 =
      Btg + (size_t)(colBase + 2 * wave * 16 + lrow) * NN + lq * 16;
  const unsigned char* bS1 = bS0 + (size_t)16 * NN;
  unsigned char* aD0 = &As[(2 * wave) * 1024];
  unsigned char* aD1 = &As[(2 * wave + 1) * 1024];
  unsigned char* bD0 = &Bs[(2 * wave) * 1024];
  unsigned char* bD1 = &Bs[(2 * wave + 1) * 1024];

  for (int kt = kStart; kt < kStart + kLen; kt += 64) {
    GLDS16(aS0 + kt, aD0);
    GLDS16(aS1 + kt, aD1);
    GLDS16(bS0 + kt, bD0);
    GLDS16(bS1 + kt, bD1);
    __syncthreads();
    for (int h = 0; h < 2; ++h) {
      const int fo = (h * 2 + (lq >> 1)) * 256 + lrow * 16 + (lq & 1) * 8;
      long af[4], bf[4];
      for (int i = 0; i < 4; ++i)
        af[i] = *(const long*)&As[(wr * 4 + i) * 1024 + fo];
      for (int j = 0; j < 4; ++j)
        bf[j] = *(const long*)&Bs[(wc * 4 + j) * 1024 + fo];
      for (int i = 0; i < 4; ++i)
        for (int j = 0; j < 4; ++j)
          acc[i][j] = __builtin_amdgcn_mfma_f32_16x16x32_fp8_fp8(
              af[i], bf[j], acc[i][j], 0, 0, 0);
    }
    __syncthreads();
  }
  // C/D layout: col = lane&15, row = (lane>>4)*4 + reg
  for (int i = 0; i < 4; ++i) {
    int r0 = rowBase + (wr * 4 + i) * 16 + lq * 4;
    for (int j = 0; j < 4; ++j) {
      int c0 = colBase + (wc * 4 + j) * 16 + lrow;
      for (int r = 0; r < 4; ++r)
        Cout[(size_t)(r0 + r) * NN + c0] = bf16bits(acc[i][j][r]);
    }
  }
}

// ---------------------------------------------------------------------------
// prep: convert A -> fp8 (straight + transposed, x2^19) + fused y1/s1
// matvec partials. grid 2304 (48x48 tiles of 64x64).
__global__ __launch_bounds__(256) void prep(
    const float* __restrict__ A, const float* __restrict__ vu,
    const float* __restrict__ vv, unsigned char* __restrict__ Af8,
    unsigned char* __restrict__ Atf8, float* __restrict__ y1,
    float* __restrict__ s1) {
  __shared__ float sh[64 * 65 + 512];
  const int bid = blockIdx.x;
  const int t = threadIdx.x;
  const int bx = (bid % 48) * 64, by = (bid / 48) * 64;
  const int rr = t >> 4;
  const int c4 = (t & 15) * 4;
  for (int it = 0; it < 4; ++it) {
    int r = rr + it * 16;
    float4 val = *(const float4*)(A + (size_t)(by + r) * NN + bx + c4);
    sh[r * 65 + c4] = val.x; sh[r * 65 + c4 + 1] = val.y;
    sh[r * 65 + c4 + 2] = val.z; sh[r * 65 + c4 + 3] = val.w;
    *(unsigned*)(Af8 + (size_t)(by + r) * NN + bx + c4) =
        pk4_f8(val.x * SCALE_A, val.y * SCALE_A, val.z * SCALE_A,
               val.w * SCALE_A);
  }
  __syncthreads();
  for (int it = 0; it < 4; ++it) {
    int c = (t >> 4) + it * 16;
    int r0 = (t & 15) * 4;
    *(unsigned*)(Atf8 + (size_t)(bx + c) * NN + by + r0) =
        pk4_f8(sh[r0 * 65 + c] * SCALE_A, sh[(r0 + 1) * 65 + c] * SCALE_A,
               sh[(r0 + 2) * 65 + c] * SCALE_A,
               sh[(r0 + 3) * 65 + c] * SCALE_A);
  }
  // fused matvec partials: y1[r] += A[r,:].v ; s1[c] += u.A[:,c]
  const int q = t >> 6;
  const int l = t & 63;
  float sy = 0.f, ss_ = 0.f;
  for (int i = 0; i < 16; ++i) {
    int c = q * 16 + i;
    sy += sh[l * 65 + c] * vv[bx + c];
    ss_ += vu[by + c] * sh[c * 65 + l];
  }
  float* red = sh + 64 * 65;
  red[q * 64 + l] = sy;
  red[256 + q * 64 + l] = ss_;
  __syncthreads();
  if (t < 64) {
    float v4 = red[t] + red[64 + t] + red[128 + t] + red[192 + t];
    atomAddF(&y1[by + t], v4);
  } else if (t < 128) {
    int cc = t - 64;
    float v4 = red[256 + cc] + red[256 + 64 + cc] + red[256 + 128 + cc] +
               red[256 + 192 + cc];
    atomAddF(&s1[bx + cc], v4);
  }
}

// ---------------------------------------------------------------------------
// gemm1 fused: [0,1152) gemm A2=A*A (split-K); [1152,1920) topk(A) layer 0.
__global__ __launch_bounds__(256) void gemm1_fused(
    const unsigned char* __restrict__ Af8,
    const unsigned char* __restrict__ Atf8, unsigned short* __restrict__ C,
    int kLen, int nGemm, const float* __restrict__ A, int* __restrict__ cnts,
    int* __restrict__ tIdx, float* __restrict__ tVal) {
  const int bid = blockIdx.x;
  if (bid < nGemm) {
    int tile = bid % 576;
    gemm_f8_body(Af8, Atf8, C, kLen, tile % 24, tile / 24, bid / 576);
  } else {
    int row = (bid - nGemm) * 4 + (threadIdx.x >> 6);
    topk_row_dev(A, 1, 0, row, threadIdx.x & 63, 1.0f, cnts, tIdx, tVal,
                 nullptr, 0.f);
  }
}

// ---------------------------------------------------------------------------
// gemm2 fused: [0,1152) gemm A3=A2*A (split-K); [1152,1920) tvec = A.y1.
__global__ __launch_bounds__(256) void gemm2_fused(
    const unsigned char* __restrict__ A2f8,
    const unsigned char* __restrict__ Atf8, unsigned short* __restrict__ C,
    int kLen, int nGemm, const float* __restrict__ A,
    const float* __restrict__ y1, float* __restrict__ tvec) {
  const int bid = blockIdx.x;
  if (bid < nGemm) {
    int tile = bid % 576;
    gemm_f8_body(A2f8, Atf8, C, kLen, tile % 24, tile / 24, bid / 576);
  } else {
    int row = (bid - nGemm) * 4 + (threadIdx.x >> 6);
    int lane = threadIdx.x & 63;
    const float4* rp = (const float4*)(A + (size_t)row * NN);
    const float4* yp = (const float4*)y1;
    float s = 0.f;
#pragma unroll
    for (int j = 0; j < 12; ++j) {
      float4 a = rp[lane + j * 64];
      float4 y = yp[lane + j * 64];
      s += a.x * y.x + a.y * y.y + a.z * y.z + a.w * y.w;
    }
    for (int off = 32; off; off >>= 1) s += __shfl_down(s, off, 64);
    if (lane == 0) tvec[row] = s;
  }
}

// ---------------------------------------------------------------------------
// post1: topk(A2 bf16 partial-sum) + fp8 cast -> A2f8 (768 blocks)
__global__ __launch_bounds__(256) void post1(
    const unsigned short* __restrict__ C, int parts,
    unsigned char* __restrict__ A2f8, int* __restrict__ cnts,
    int* __restrict__ tIdx, float* __restrict__ tVal) {
  int row = blockIdx.x * 4 + (threadIdx.x >> 6);
  topk_row_dev(C, parts, 1, row, threadIdx.x & 63, DESCALE38, cnts, tIdx,
               tVal, A2f8, F8SCALE2);
}

// ---------------------------------------------------------------------------
// post2: [0,768) topk(A3 bf16 partial-sum); [768] w0..w3
__global__ __launch_bounds__(256) void post2(
    const unsigned short* __restrict__ C, int parts,
    const float* __restrict__ vu, const float* __restrict__ vv,
    const float* __restrict__ y1, const float* __restrict__ s1,
    const float* __restrict__ tvec, int* __restrict__ cnts,
    int* __restrict__ tIdx, float* __restrict__ tVal,
    float* __restrict__ wacc) {
  const int bid = blockIdx.x;
  const int t = threadIdx.x;
  if (bid < 768) {
    int row = bid * 4 + (t >> 6);
    topk_row_dev(C, parts, 1, row, t & 63, DESCALE38, cnts, tIdx, tVal,
                 nullptr, 0.f);
  } else {
    __shared__ float red4[4];
    float w0 = row_dot_f32(vu, vv, red4);  __syncthreads();
    float w1 = row_dot_f32(vu, y1, red4);  __syncthreads();
    float w2 = row_dot_f32(s1, y1, red4);  __syncthreads();
    float w3 = row_dot_f32(s1, tvec, red4);
    if (t == 0) { wacc[0] = w0; wacc[1] = w1; wacc[2] = w2; wacc[3] = w3; }
  }
}

// ---------------------------------------------------------------------------
static __device__ inline float ldE(const float* __restrict__ ue,
                                   const float* __restrict__ ie, int r, int d) {
  return r < NU ? ue[(size_t)r * DD + d] : ie[(size_t)(r - NU) * DD + d];
}

__global__ __launch_bounds__(128) void build_light(
    const float* __restrict__ uemb, const float* __restrict__ iemb,
    const float* __restrict__ uemb0, const float* __restrict__ iemb0,
    const float* __restrict__ wacc, const int* __restrict__ cnts,
    const int* __restrict__ tIdx, const float* __restrict__ tVal,
    float* __restrict__ lightOut) {
  float w0 = wacc[0], w1 = wacc[1], w2 = wacc[2], w3 = wacc[3];
  float ss = w0 + w1 + w2 + w3;
  w0 /= ss; w1 /= ss; w2 /= ss; w3 /= ss;
  float m = fmaxf(fmaxf(w0, w1), fmaxf(w2, w3));
  float e0 = expf(w0 - m), e1 = expf(w1 - m), e2 = expf(w2 - m),
        e3 = expf(w3 - m);
  float se = e0 + e1 + e2 + e3;
  float aw[4] = {e0 / se, e1 / se, e2 / se, e3 / se};
  float aw4 = GAMMA_F * (aw[1] + aw[2] + aw[3]);

  int row = blockIdx.x, d = threadIdx.x;
  float acc = aw[0] * ldE(uemb, iemb, row, d) +
              aw4 * ldE(uemb0, iemb0, row, d);
  __shared__ int sIdx[128];
  __shared__ float sVal[128];
  for (int l = 0; l < 3; ++l) {
    int c = cnts[l * NN + row];
    const int* ip = tIdx + ((size_t)l * NN + row) * 128;
    const float* vp = tVal + ((size_t)l * NN + row) * 128;
    __syncthreads();
    if (d < c) { sIdx[d] = ip[d]; sVal[d] = vp[d]; }
    __syncthreads();
    float al = aw[l + 1];
    float la = 0.f;
    for (int k = 0; k < c; ++k) la += sVal[k] * ldE(uemb, iemb, sIdx[k], d);
    acc += al * la;
  }
  lightOut[(size_t)row * DD + d] = acc;
}

__global__ __launch_bounds__(256) void out_dot(const int* __restrict__ users,
                                               const int* __restrict__ items,
                                               const float* __restrict__ lightOut,
                                               float* __restrict__ out) {
  int b = blockIdx.x * 4 + (threadIdx.x >> 6);
  int lane = threadIdx.x & 63;
  const float* up = lightOut + (size_t)users[b] * DD;
  const float* ip = lightOut + (size_t)(NU + items[b]) * DD;
  float s = up[lane] * ip[lane] + up[lane + 64] * ip[lane + 64];
  for (int off = 32; off; off >>= 1) s += __shfl_down(s, off, 64);
  if (lane == 0) out[b] = s;
}

// ---------------------------------------------------------------------------
extern "C" void kernel_launch(void* const* d_in, const int* in_sizes, int n_in,
                              void* d_out, int out_size, void* d_ws,
                              size_t ws_size, hipStream_t stream) {
  const int* users = (const int*)d_in[0];
  const int* items = (const int*)d_in[1];
  const float* A = (const float*)d_in[2];
  const float* uemb = (const float*)d_in[3];
  const float* iemb = (const float*)d_in[4];
  const float* uemb0 = (const float*)d_in[5];
  const float* iemb0 = (const float*)d_in[6];
  const float* vu = (const float*)d_in[7];
  const float* vv = (const float*)d_in[8];
  float* out = (float*)d_out;

  char* ws = (char*)d_ws;
  size_t off = 0;
  auto alloc = [&](size_t bytes) -> void* {
    void* p = ws + off;
    off += (bytes + 255) & ~(size_t)255;
    return p;
  };
  unsigned char* Af8 = (unsigned char*)alloc((size_t)NN * NN);
  unsigned char* Atf8 = (unsigned char*)alloc((size_t)NN * NN);
  unsigned char* A2f8 = (unsigned char*)alloc((size_t)NN * NN);
  float* y1 = (float*)alloc((size_t)NN * 4);   // contiguous with s1
  float* s1 = (float*)alloc((size_t)NN * 4);
  float* tvec = (float*)alloc((size_t)NN * 4);
  float* wacc = (float*)alloc(256);
  int* cnts = (int*)alloc((size_t)3 * NN * 4);
  int* tIdx = (int*)alloc((size_t)3 * NN * 128 * 4);
  float* tVal = (float*)alloc((size_t)3 * NN * 128 * 4);
  float* lightOut = (float*)alloc((size_t)NN * DD * 4);

  const size_t cBytes = (size_t)NN * NN * 2;  // bf16 partials
  int kParts = (ws_size >= off + 2 * cBytes + 512) ? 2 : 1;
  unsigned short* C = (unsigned short*)alloc((size_t)kParts * cBytes);
  const int kLen = NN / kParts;
  const int nGemm = 576 * kParts;

  // 1) zero y1/s1 (contiguous 2*NN floats)
  hipMemsetAsync(y1, 0, (size_t)2 * NN * 4, stream);
  // 2) prep: A -> fp8 (straight+transposed) + y1/s1 partials
  prep<<<2304, 256, 0, stream>>>(A, vu, vv, Af8, Atf8, y1, s1);
  // 3) gemm1 (A2=A*A, bf16 partials) | topk(A) layer 0
  gemm1_fused<<<nGemm + 768, 256, 0, stream>>>(Af8, Atf8, C, kLen, nGemm, A,
                                               cnts, tIdx, tVal);
  // 4) post1: topk(A2) + fp8 cast -> A2f8
  post1<<<768, 256, 0, stream>>>(C, kParts, A2f8, cnts + NN,
                                 tIdx + (size_t)NN * 128,
                                 tVal + (size_t)NN * 128);
  // 5) gemm2 (A3=A2*A) | tvec = A.y1
  gemm2_fused<<<nGemm + 768, 256, 0, stream>>>(A2f8, Atf8, C, kLen, nGemm, A,
                                               y1, tvec);
  // 6) post2: topk(A3) | w0..w3
  post2<<<769, 256, 0, stream>>>(C, kParts, vu, vv, y1, s1, tvec,
                                 cnts + 2 * NN, tIdx + (size_t)2 * NN * 128,
                                 tVal + (size_t)2 * NN * 128, wacc);
  // 7) light_out (attn softmax inlined)
  build_light<<<NN, 128, 0, stream>>>(uemb, iemb, uemb0, iemb0, wacc, cnts,
                                      tIdx, tVal, lightOut);
  // 8) gather dots
  out_dot<<<BB / 4, 256, 0, stream>>>(users, items, lightOut, out);
}

// Round 11
// 375.129 us; speedup vs baseline: 1.3621x; 1.3621x over previous
//
#include <hip/hip_runtime.h>
#include <hip/hip_fp8.h>
#include <math.h>

#define NN 3072
#define NU 1024
#define NI 2048
#define DD 128
#define BB 8192
#define GAMMA_F 0.2f

#define SCALE_A 524288.0f                // 2^19
#define F8SCALE2 1.9073486328125e-06f    // 2^-19  (C*2^38 -> A2*2^19 for fp8)
#define DESCALE38 3.637978807091713e-12f // 2^-38  (C -> true A^k values)

typedef __attribute__((ext_vector_type(4))) float f32x4;

// async global->LDS, 16B per lane; LDS dst = wave-uniform base + lane*16
#define GLDS16(g, l)                                                          \
  __builtin_amdgcn_global_load_lds(                                           \
      (__attribute__((address_space(1))) void*)(g),                           \
      (__attribute__((address_space(3))) void*)(l), 16, 0, 0)

static __device__ inline unsigned short bf16bits(float x) {
  union { unsigned u; float f; } cv;
  cv.f = x;
  unsigned r = cv.u + 0x7fff + ((cv.u >> 16) & 1);  // RNE
  return (unsigned short)(r >> 16);
}

// pack 4 floats -> 4 fp8 e4m3 (OCP) bytes
static __device__ inline unsigned pk4_f8(float a, float b, float c, float d) {
#if defined(__has_builtin)
#if __has_builtin(__builtin_amdgcn_cvt_pk_fp8_f32)
  int p = __builtin_amdgcn_cvt_pk_fp8_f32(a, b, 0, false);
  p = __builtin_amdgcn_cvt_pk_fp8_f32(c, d, p, true);
  return (unsigned)p;
#else
  return (unsigned)__hip_fp8_e4m3(a).__x | ((unsigned)__hip_fp8_e4m3(b).__x << 8) |
         ((unsigned)__hip_fp8_e4m3(c).__x << 16) |
         ((unsigned)__hip_fp8_e4m3(d).__x << 24);
#endif
#else
  return (unsigned)__hip_fp8_e4m3(a).__x | ((unsigned)__hip_fp8_e4m3(b).__x << 8) |
         ((unsigned)__hip_fp8_e4m3(c).__x << 16) |
         ((unsigned)__hip_fp8_e4m3(d).__x << 24);
#endif
}

// fast fp32 global atomic add (tiny y1/s1 accumulators only)
static __device__ inline void atomAddF(float* p, float v) {
#if defined(__has_builtin)
#if __has_builtin(__builtin_amdgcn_global_atomic_fadd_f32)
  __builtin_amdgcn_global_atomic_fadd_f32(
      (__attribute__((address_space(1))) float*)p, v);
#else
  unsafeAtomicAdd(p, v);
#endif
#else
  unsafeAtomicAdd(p, v);
#endif
}

static __device__ inline float block_sum(float s, float* red4) {
  int tid = threadIdx.x;
  for (int off = 32; off; off >>= 1) s += __shfl_down(s, off, 64);
  if ((tid & 63) == 0) red4[tid >> 6] = s;
  __syncthreads();
  return red4[0] + red4[1] + red4[2] + red4[3];
}

static __device__ inline float row_dot_f32(const float* __restrict__ a,
                                           const float* __restrict__ b,
                                           float* red4) {
  const float4* ap = (const float4*)a;
  const float4* bp = (const float4*)b;
  float s = 0.f;
  for (int j = threadIdx.x; j < NN / 4; j += 256) {
    float4 x = ap[j], y = bp[j];
    s += x.x * y.x + x.y * y.y + x.z * y.z + x.w * y.w;
  }
  return block_sum(s, red4);
}

// ---------------------------------------------------------------------------
// Per-row top-64 via radix select on bits [30..16] with wave OR/AND
// prefix-skip; one wave per row; keys compared as f's own bits (no shadow).
// bf=1: base = bf16 partials (parts buffers). bf=0: fp32 matrix.
static __device__ void topk_row_dev(const void* __restrict__ base, int parts,
                                    int bf, int row, int lane, float descale,
                                    int* __restrict__ outCnt,
                                    int* __restrict__ outIdx,
                                    float* __restrict__ outVal,
                                    unsigned char* __restrict__ outF8,
                                    float f8scale) {
  float f[48];
  if (bf) {
    const unsigned short* b0 = (const unsigned short*)base;
    const uint4* r0 = (const uint4*)(b0 + (size_t)row * NN);
#pragma unroll
    for (int j = 0; j < 6; ++j) {
      uint4 q = r0[lane + j * 64];
      unsigned uu[4] = {q.x, q.y, q.z, q.w};
#pragma unroll
      for (int e = 0; e < 4; ++e) {
        f[j * 8 + e * 2] = __uint_as_float(uu[e] << 16);
        f[j * 8 + e * 2 + 1] = __uint_as_float(uu[e] & 0xffff0000u);
      }
    }
    for (int p = 1; p < parts; ++p) {
      const uint4* rp =
          (const uint4*)(b0 + (size_t)p * NN * NN + (size_t)row * NN);
#pragma unroll
      for (int j = 0; j < 6; ++j) {
        uint4 q = rp[lane + j * 64];
        unsigned uu[4] = {q.x, q.y, q.z, q.w};
#pragma unroll
        for (int e = 0; e < 4; ++e) {
          f[j * 8 + e * 2] += __uint_as_float(uu[e] << 16);
          f[j * 8 + e * 2 + 1] += __uint_as_float(uu[e] & 0xffff0000u);
        }
      }
    }
  } else {
    const float4* r0 = (const float4*)((const float*)base + (size_t)row * NN);
#pragma unroll
    for (int j = 0; j < 12; ++j) {
      float4 a = r0[lane + j * 64];
      f[j * 4 + 0] = a.x; f[j * 4 + 1] = a.y;
      f[j * 4 + 2] = a.z; f[j * 4 + 3] = a.w;
    }
  }
  if (outF8) {
    // bf path layout: f[j*8+e] = col (j*64+lane)*8 + e
    uint2* ob = (uint2*)(outF8 + (size_t)row * NN);
#pragma unroll
    for (int j = 0; j < 6; ++j) {
      uint2 w;
      w.x = pk4_f8(f[j * 8 + 0] * f8scale, f[j * 8 + 1] * f8scale,
                   f[j * 8 + 2] * f8scale, f[j * 8 + 3] * f8scale);
      w.y = pk4_f8(f[j * 8 + 4] * f8scale, f[j * 8 + 5] * f8scale,
                   f[j * 8 + 6] * f8scale, f[j * 8 + 7] * f8scale);
      ob[lane + j * 64] = w;
    }
  }
  // wave-wide OR / AND of keys -> constant-prefix skip
  unsigned bor = 0, band = 0xffffffffu;
#pragma unroll
  for (int r = 0; r < 48; ++r) {
    unsigned k = __float_as_uint(f[r]);
    bor |= k; band &= k;
  }
  for (int off = 32; off; off >>= 1) {
    bor |= (unsigned)__shfl_down((int)bor, off, 64);
    band &= (unsigned)__shfl_down((int)band, off, 64);
  }
  bor = (unsigned)__shfl((int)bor, 0, 64);
  band = (unsigned)__shfl((int)band, 0, 64);
  unsigned diff = bor ^ band;
  int hi = diff ? (31 - __clz(diff)) : 16;
  if (hi < 16) hi = 16;
  if (hi > 30) hi = 30;
  unsigned t = band & ~((hi < 31) ? ((2u << hi) - 1u) : 0xffffffffu);

  for (int b = hi; b >= 16; --b) {
    unsigned cand = t | (1u << b);
    int c = 0;
#pragma unroll
    for (int r = 0; r < 48; ++r) c += (__float_as_uint(f[r]) >= cand) ? 1 : 0;
    for (int off = 32; off; off >>= 1) c += __shfl_down(c, off, 64);
    c = __shfl(c, 0, 64);
    if (c >= 64) t = cand;
  }
  int basec = 0;
  int* oi = outIdx + (size_t)row * 128;
  float* ov = outVal + (size_t)row * 128;
#pragma unroll
  for (int r = 0; r < 48; ++r) {
    bool keep = __float_as_uint(f[r]) >= t;
    unsigned long long m = __ballot(keep);
    if (keep) {
      int pos = basec + __popcll(m & ((1ull << lane) - 1ull));
      if (pos < 128) {
        oi[pos] = bf ? ((r >> 3) * 512 + lane * 8 + (r & 7))
                     : ((r >> 2) * 256 + lane * 4 + (r & 3));
        ov[pos] = f[r] * descale;
      }
    }
    basec += __popcll(m);
  }
  if (lane == 0) outCnt[row] = basec < 128 ? basec : 128;
}

// ---------------------------------------------------------------------------
// prep: convert A -> fp8 (straight + transposed, x2^19) + fused y1/s1
// matvec partials. grid 2304 (48x48 tiles of 64x64). Conv-only: low VGPR
// (NEVER fuse high-VGPR roles here or into the GEMM -- R10 regression).
__global__ __launch_bounds__(256) void prep(
    const float* __restrict__ A, const float* __restrict__ vu,
    const float* __restrict__ vv, unsigned char* __restrict__ Af8,
    unsigned char* __restrict__ Atf8, float* __restrict__ y1,
    float* __restrict__ s1) {
  __shared__ float sh[64 * 65 + 512];
  const int bid = blockIdx.x;
  const int t = threadIdx.x;
  const int bx = (bid % 48) * 64, by = (bid / 48) * 64;
  const int rr = t >> 4;
  const int c4 = (t & 15) * 4;
  for (int it = 0; it < 4; ++it) {
    int r = rr + it * 16;
    float4 val = *(const float4*)(A + (size_t)(by + r) * NN + bx + c4);
    sh[r * 65 + c4] = val.x; sh[r * 65 + c4 + 1] = val.y;
    sh[r * 65 + c4 + 2] = val.z; sh[r * 65 + c4 + 3] = val.w;
    *(unsigned*)(Af8 + (size_t)(by + r) * NN + bx + c4) =
        pk4_f8(val.x * SCALE_A, val.y * SCALE_A, val.z * SCALE_A,
               val.w * SCALE_A);
  }
  __syncthreads();
  for (int it = 0; it < 4; ++it) {
    int c = (t >> 4) + it * 16;
    int r0 = (t & 15) * 4;
    *(unsigned*)(Atf8 + (size_t)(bx + c) * NN + by + r0) =
        pk4_f8(sh[r0 * 65 + c] * SCALE_A, sh[(r0 + 1) * 65 + c] * SCALE_A,
               sh[(r0 + 2) * 65 + c] * SCALE_A,
               sh[(r0 + 3) * 65 + c] * SCALE_A);
  }
  // fused matvec partials: y1[r] += A[r,:].v ; s1[c] += u.A[:,c]
  const int q = t >> 6;
  const int l = t & 63;
  float sy = 0.f, ss_ = 0.f;
  for (int i = 0; i < 16; ++i) {
    int c = q * 16 + i;
    sy += sh[l * 65 + c] * vv[bx + c];
    ss_ += vu[by + c] * sh[c * 65 + l];
  }
  float* red = sh + 64 * 65;
  red[q * 64 + l] = sy;
  red[256 + q * 64 + l] = ss_;
  __syncthreads();
  if (t < 64) {
    float v4 = red[t] + red[64 + t] + red[128 + t] + red[192 + t];
    atomAddF(&y1[by + t], v4);
  } else if (t < 128) {
    int cc = t - 64;
    float v4 = red[256 + cc] + red[256 + 64 + cc] + red[256 + 128 + cc] +
               red[256 + 192 + cc];
    atomAddF(&s1[bx + cc], v4);
  }
}

// ---------------------------------------------------------------------------
// fp8 GEMM: C(128x128 tile, bf16) = A(row-major fp8) * Bt(row-major fp8=B^T),
// BK=128 (12 iters at kParts=2 -> half the barrier drains of BK=64);
// split-K over blockIdx.z writing separate bf16 partial buffers.
// LDS 16KB/operand: chunk c = mt*2 + h2 (mtile mt: 16 rows; k-half h2: 64 k)
// at c*1024; within chunk addr = (k16)*256 + row*16 + (k%16).
__global__ __launch_bounds__(256) void gemm_f8(
    const unsigned char* __restrict__ Ag,
    const unsigned char* __restrict__ Btg,
    unsigned short* __restrict__ Cg, int kLen) {
  __shared__ __align__(16) unsigned char As[16384];
  __shared__ __align__(16) unsigned char Bs[16384];

  const int tid = threadIdx.x;
  const int wave = tid >> 6;
  const int lane = tid & 63;
  const int rowBase = blockIdx.y * 128;
  const int colBase = blockIdx.x * 128;
  const int wr = wave >> 1, wc = wave & 1;
  const int lrow = lane & 15, lq = lane >> 4;
  const int kStart = blockIdx.z * kLen;
  unsigned short* Cout = Cg + (size_t)blockIdx.z * NN * NN;

  f32x4 acc[4][4];
  for (int i = 0; i < 4; ++i)
    for (int j = 0; j < 4; ++j) acc[i][j] = (f32x4){0.f, 0.f, 0.f, 0.f};

  // wave stages mtiles 2w, 2w+1 of A and B; each mtile = 2 chunks (k-halves)
  const unsigned char* aB =
      Ag + (size_t)(rowBase + 2 * wave * 16 + lrow) * NN + lq * 16;
  const unsigned char* bB =
      Btg + (size_t)(colBase + 2 * wave * 16 + lrow) * NN + lq * 16;
  unsigned char* aD = &As[(2 * wave) * 2048];
  unsigned char* bD = &Bs[(2 * wave) * 2048];

  for (int kt = kStart; kt < kStart + kLen; kt += 128) {
    GLDS16(aB + kt, aD);
    GLDS16(aB + kt + 64, aD + 1024);
    GLDS16(aB + (size_t)16 * NN + kt, aD + 2048);
    GLDS16(aB + (size_t)16 * NN + kt + 64, aD + 3072);
    GLDS16(bB + kt, bD);
    GLDS16(bB + kt + 64, bD + 1024);
    GLDS16(bB + (size_t)16 * NN + kt, bD + 2048);
    GLDS16(bB + (size_t)16 * NN + kt + 64, bD + 3072);
    __syncthreads();
    for (int h = 0; h < 4; ++h) {
      const int fo = (h >> 1) * 1024 + ((h & 1) * 2 + (lq >> 1)) * 256 +
                     lrow * 16 + (lq & 1) * 8;
      long af[4], bf[4];
      for (int i = 0; i < 4; ++i)
        af[i] = *(const long*)&As[(wr * 4 + i) * 2048 + fo];
      for (int j = 0; j < 4; ++j)
        bf[j] = *(const long*)&Bs[(wc * 4 + j) * 2048 + fo];
      for (int i = 0; i < 4; ++i)
        for (int j = 0; j < 4; ++j)
          acc[i][j] = __builtin_amdgcn_mfma_f32_16x16x32_fp8_fp8(
              af[i], bf[j], acc[i][j], 0, 0, 0);
    }
    __syncthreads();
  }
  // C/D layout: col = lane&15, row = (lane>>4)*4 + reg (dtype-independent)
  for (int i = 0; i < 4; ++i) {
    int r0 = rowBase + (wr * 4 + i) * 16 + lq * 4;
    for (int j = 0; j < 4; ++j) {
      int c0 = colBase + (wc * 4 + j) * 16 + lrow;
      for (int r = 0; r < 4; ++r)
        Cout[(size_t)(r0 + r) * NN + c0] = bf16bits(acc[i][j][r]);
    }
  }
}

// ---------------------------------------------------------------------------
// post1: [0,768)    topk(A2 bf16 partial-sum) + fp8 cast -> A2f8
//        [768,1536) topk(A fp32)  (layer 0)
//        [1536,2304) tvec = A.y1 (one wave per row)
__global__ __launch_bounds__(256) void post1(
    const unsigned short* __restrict__ C, int parts,
    const float* __restrict__ A, const float* __restrict__ y1,
    unsigned char* __restrict__ A2f8, int* __restrict__ cnts,
    int* __restrict__ tIdx, float* __restrict__ tVal,
    float* __restrict__ tvec) {
  const int bid = blockIdx.x;
  const int t = threadIdx.x;
  if (bid < 768) {
    int row = bid * 4 + (t >> 6);
    topk_row_dev(C, parts, 1, row, t & 63, DESCALE38, cnts + NN,
                 tIdx + (size_t)NN * 128, tVal + (size_t)NN * 128, A2f8,
                 F8SCALE2);
  } else if (bid < 1536) {
    int row = (bid - 768) * 4 + (t >> 6);
    topk_row_dev(A, 1, 0, row, t & 63, 1.0f, cnts, tIdx, tVal, nullptr, 0.f);
  } else {
    int row = (bid - 1536) * 4 + (t >> 6);
    int lane = t & 63;
    const float4* rp = (const float4*)(A + (size_t)row * NN);
    const float4* yp = (const float4*)y1;
    float s = 0.f;
#pragma unroll
    for (int j = 0; j < 12; ++j) {
      float4 a = rp[lane + j * 64];
      float4 y = yp[lane + j * 64];
      s += a.x * y.x + a.y * y.y + a.z * y.z + a.w * y.w;
    }
    for (int off = 32; off; off >>= 1) s += __shfl_down(s, off, 64);
    if (lane == 0) tvec[row] = s;
  }
}

// ---------------------------------------------------------------------------
// post2: [0,768) topk(A3 bf16 partial-sum); [768] w0..w3
__global__ __launch_bounds__(256) void post2(
    const unsigned short* __restrict__ C, int parts,
    const float* __restrict__ vu, const float* __restrict__ vv,
    const float* __restrict__ y1, const float* __restrict__ s1,
    const float* __restrict__ tvec, int* __restrict__ cnts,
    int* __restrict__ tIdx, float* __restrict__ tVal,
    float* __restrict__ wacc) {
  const int bid = blockIdx.x;
  const int t = threadIdx.x;
  if (bid < 768) {
    int row = bid * 4 + (t >> 6);
    topk_row_dev(C, parts, 1, row, t & 63, DESCALE38, cnts, tIdx, tVal,
                 nullptr, 0.f);
  } else {
    __shared__ float red4[4];
    float w0 = row_dot_f32(vu, vv, red4);  __syncthreads();
    float w1 = row_dot_f32(vu, y1, red4);  __syncthreads();
    float w2 = row_dot_f32(s1, y1, red4);  __syncthreads();
    float w3 = row_dot_f32(s1, tvec, red4);
    if (t == 0) { wacc[0] = w0; wacc[1] = w1; wacc[2] = w2; wacc[3] = w3; }
  }
}

// ---------------------------------------------------------------------------
static __device__ inline float ldE(const float* __restrict__ ue,
                                   const float* __restrict__ ie, int r, int d) {
  return r < NU ? ue[(size_t)r * DD + d] : ie[(size_t)(r - NU) * DD + d];
}

__global__ __launch_bounds__(128) void build_light(
    const float* __restrict__ uemb, const float* __restrict__ iemb,
    const float* __restrict__ uemb0, const float* __restrict__ iemb0,
    const float* __restrict__ wacc, const int* __restrict__ cnts,
    const int* __restrict__ tIdx, const float* __restrict__ tVal,
    float* __restrict__ lightOut) {
  float w0 = wacc[0], w1 = wacc[1], w2 = wacc[2], w3 = wacc[3];
  float ss = w0 + w1 + w2 + w3;
  w0 /= ss; w1 /= ss; w2 /= ss; w3 /= ss;
  float m = fmaxf(fmaxf(w0, w1), fmaxf(w2, w3));
  float e0 = expf(w0 - m), e1 = expf(w1 - m), e2 = expf(w2 - m),
        e3 = expf(w3 - m);
  float se = e0 + e1 + e2 + e3;
  float aw[4] = {e0 / se, e1 / se, e2 / se, e3 / se};
  float aw4 = GAMMA_F * (aw[1] + aw[2] + aw[3]);

  int row = blockIdx.x, d = threadIdx.x;
  float acc = aw[0] * ldE(uemb, iemb, row, d) +
              aw4 * ldE(uemb0, iemb0, row, d);
  __shared__ int sIdx[128];
  __shared__ float sVal[128];
  for (int l = 0; l < 3; ++l) {
    int c = cnts[l * NN + row];
    const int* ip = tIdx + ((size_t)l * NN + row) * 128;
    const float* vp = tVal + ((size_t)l * NN + row) * 128;
    __syncthreads();
    if (d < c) { sIdx[d] = ip[d]; sVal[d] = vp[d]; }
    __syncthreads();
    float al = aw[l + 1];
    float la = 0.f;
    for (int k = 0; k < c; ++k) la += sVal[k] * ldE(uemb, iemb, sIdx[k], d);
    acc += al * la;
  }
  lightOut[(size_t)row * DD + d] = acc;
}

__global__ __launch_bounds__(256) void out_dot(const int* __restrict__ users,
                                               const int* __restrict__ items,
                                               const float* __restrict__ lightOut,
                                               float* __restrict__ out) {
  int b = blockIdx.x * 4 + (threadIdx.x >> 6);
  int lane = threadIdx.x & 63;
  const float* up = lightOut + (size_t)users[b] * DD;
  const float* ip = lightOut + (size_t)(NU + items[b]) * DD;
  float s = up[lane] * ip[lane] + up[lane + 64] * ip[lane + 64];
  for (int off = 32; off; off >>= 1) s += __shfl_down(s, off, 64);
  if (lane == 0) out[b] = s;
}

// ---------------------------------------------------------------------------
extern "C" void kernel_launch(void* const* d_in, const int* in_sizes, int n_in,
                              void* d_out, int out_size, void* d_ws,
                              size_t ws_size, hipStream_t stream) {
  const int* users = (const int*)d_in[0];
  const int* items = (const int*)d_in[1];
  const float* A = (const float*)d_in[2];
  const float* uemb = (const float*)d_in[3];
  const float* iemb = (const float*)d_in[4];
  const float* uemb0 = (const float*)d_in[5];
  const float* iemb0 = (const float*)d_in[6];
  const float* vu = (const float*)d_in[7];
  const float* vv = (const float*)d_in[8];
  float* out = (float*)d_out;

  char* ws = (char*)d_ws;
  size_t off = 0;
  auto alloc = [&](size_t bytes) -> void* {
    void* p = ws + off;
    off += (bytes + 255) & ~(size_t)255;
    return p;
  };
  unsigned char* Af8 = (unsigned char*)alloc((size_t)NN * NN);
  unsigned char* Atf8 = (unsigned char*)alloc((size_t)NN * NN);
  unsigned char* A2f8 = (unsigned char*)alloc((size_t)NN * NN);
  float* y1 = (float*)alloc((size_t)NN * 4);   // contiguous with s1
  float* s1 = (float*)alloc((size_t)NN * 4);
  float* tvec = (float*)alloc((size_t)NN * 4);
  float* wacc = (float*)alloc(256);
  int* cnts = (int*)alloc((size_t)3 * NN * 4);
  int* tIdx = (int*)alloc((size_t)3 * NN * 128 * 4);
  float* tVal = (float*)alloc((size_t)3 * NN * 128 * 4);
  float* lightOut = (float*)alloc((size_t)NN * DD * 4);

  const size_t cBytes = (size_t)NN * NN * 2;  // bf16 partials
  int kParts = (ws_size >= off + 2 * cBytes + 512) ? 2 : 1;
  unsigned short* C = (unsigned short*)alloc((size_t)kParts * cBytes);
  const int kLen = NN / kParts;

  // 1) zero y1/s1 (contiguous 2*NN floats)
  hipMemsetAsync(y1, 0, (size_t)2 * NN * 4, stream);
  // 2) prep: A -> fp8 (straight+transposed) + y1/s1 partials
  prep<<<2304, 256, 0, stream>>>(A, vu, vv, Af8, Atf8, y1, s1);
  // 3) A2 = A*A (fp8 MFMA BK=128, bf16 partials x2)
  gemm_f8<<<dim3(24, 24, kParts), 256, 0, stream>>>(Af8, Atf8, C, kLen);
  // 4) post1: topk(A2)+fp8 cast | topk(A) | tvec = A.y1
  post1<<<2304, 256, 0, stream>>>(C, kParts, A, y1, A2f8, cnts, tIdx, tVal,
                                  tvec);
  // 5) A3 = A2*A (overwrite partials)
  gemm_f8<<<dim3(24, 24, kParts), 256, 0, stream>>>(A2f8, Atf8, C, kLen);
  // 6) post2: topk(A3) | w0..w3
  post2<<<769, 256, 0, stream>>>(C, kParts, vu, vv, y1, s1, tvec,
                                 cnts + 2 * NN, tIdx + (size_t)2 * NN * 128,
                                 tVal + (size_t)2 * NN * 128, wacc);
  // 7) light_out (attn softmax inlined)
  build_light<<<NN, 128, 0, stream>>>(uemb, iemb, uemb0, iemb0, wacc, cnts,
                                      tIdx, tVal, lightOut);
  // 8) gather dots
  out_dot<<<BB / 4, 256, 0, stream>>>(users, items, lightOut, out);
}

// Round 12
// 339.749 us; speedup vs baseline: 1.5039x; 1.1041x over previous
//
#include <hip/hip_runtime.h>
#include <hip/hip_fp8.h>
#include <math.h>

#define NN 3072
#define NU 1024
#define NI 2048
#define DD 128
#define BB 8192
#define GAMMA_F 0.2f

#define SCALE_A 524288.0f                // 2^19
#define F8SCALE2 1.9073486328125e-06f    // 2^-19  (C*2^38 -> A2*2^19 for fp8)
#define DESCALE38 3.637978807091713e-12f // 2^-38  (C -> true A^k values)

typedef __attribute__((ext_vector_type(4))) float f32x4;
typedef __attribute__((ext_vector_type(16))) float f32x16;
typedef __attribute__((ext_vector_type(4))) int i32x4;
typedef __attribute__((ext_vector_type(8))) int i32x8;

// async global->LDS, 16B per lane; LDS dst = wave-uniform base + lane*16
#define GLDS16(g, l)                                                          \
  __builtin_amdgcn_global_load_lds(                                           \
      (__attribute__((address_space(1))) void*)(g),                           \
      (__attribute__((address_space(3))) void*)(l), 16, 0, 0)

static __device__ inline unsigned short bf16bits(float x) {
  union { unsigned u; float f; } cv;
  cv.f = x;
  unsigned r = cv.u + 0x7fff + ((cv.u >> 16) & 1);  // RNE
  return (unsigned short)(r >> 16);
}

// pack 4 floats -> 4 fp8 e4m3 (OCP) bytes
static __device__ inline unsigned pk4_f8(float a, float b, float c, float d) {
#if defined(__has_builtin)
#if __has_builtin(__builtin_amdgcn_cvt_pk_fp8_f32)
  int p = __builtin_amdgcn_cvt_pk_fp8_f32(a, b, 0, false);
  p = __builtin_amdgcn_cvt_pk_fp8_f32(c, d, p, true);
  return (unsigned)p;
#else
  return (unsigned)__hip_fp8_e4m3(a).__x | ((unsigned)__hip_fp8_e4m3(b).__x << 8) |
         ((unsigned)__hip_fp8_e4m3(c).__x << 16) |
         ((unsigned)__hip_fp8_e4m3(d).__x << 24);
#endif
#else
  return (unsigned)__hip_fp8_e4m3(a).__x | ((unsigned)__hip_fp8_e4m3(b).__x << 8) |
         ((unsigned)__hip_fp8_e4m3(c).__x << 16) |
         ((unsigned)__hip_fp8_e4m3(d).__x << 24);
#endif
}

// fast fp32 global atomic add (tiny y1/s1 accumulators only)
static __device__ inline void atomAddF(float* p, float v) {
#if defined(__has_builtin)
#if __has_builtin(__builtin_amdgcn_global_atomic_fadd_f32)
  __builtin_amdgcn_global_atomic_fadd_f32(
      (__attribute__((address_space(1))) float*)p, v);
#else
  unsafeAtomicAdd(p, v);
#endif
#else
  unsafeAtomicAdd(p, v);
#endif
}

static __device__ inline float block_sum(float s, float* red4) {
  int tid = threadIdx.x;
  for (int off = 32; off; off >>= 1) s += __shfl_down(s, off, 64);
  if ((tid & 63) == 0) red4[tid >> 6] = s;
  __syncthreads();
  return red4[0] + red4[1] + red4[2] + red4[3];
}

static __device__ inline float row_dot_f32(const float* __restrict__ a,
                                           const float* __restrict__ b,
                                           float* red4) {
  const float4* ap = (const float4*)a;
  const float4* bp = (const float4*)b;
  float s = 0.f;
  for (int j = threadIdx.x; j < NN / 4; j += 256) {
    float4 x = ap[j], y = bp[j];
    s += x.x * y.x + x.y * y.y + x.z * y.z + x.w * y.w;
  }
  return block_sum(s, red4);
}

// ---------------------------------------------------------------------------
// Per-row top-64 via radix select on bits [30..16] with wave OR/AND
// prefix-skip; one wave per row; keys compared as f's own bits (no shadow).
// bf=1: base = bf16 partials (parts buffers). bf=0: fp32 matrix.
static __device__ void topk_row_dev(const void* __restrict__ base, int parts,
                                    int bf, int row, int lane, float descale,
                                    int* __restrict__ outCnt,
                                    int* __restrict__ outIdx,
                                    float* __restrict__ outVal,
                                    unsigned char* __restrict__ outF8,
                                    float f8scale) {
  float f[48];
  if (bf) {
    const unsigned short* b0 = (const unsigned short*)base;
    const uint4* r0 = (const uint4*)(b0 + (size_t)row * NN);
#pragma unroll
    for (int j = 0; j < 6; ++j) {
      uint4 q = r0[lane + j * 64];
      unsigned uu[4] = {q.x, q.y, q.z, q.w};
#pragma unroll
      for (int e = 0; e < 4; ++e) {
        f[j * 8 + e * 2] = __uint_as_float(uu[e] << 16);
        f[j * 8 + e * 2 + 1] = __uint_as_float(uu[e] & 0xffff0000u);
      }
    }
    for (int p = 1; p < parts; ++p) {
      const uint4* rp =
          (const uint4*)(b0 + (size_t)p * NN * NN + (size_t)row * NN);
#pragma unroll
      for (int j = 0; j < 6; ++j) {
        uint4 q = rp[lane + j * 64];
        unsigned uu[4] = {q.x, q.y, q.z, q.w};
#pragma unroll
        for (int e = 0; e < 4; ++e) {
          f[j * 8 + e * 2] += __uint_as_float(uu[e] << 16);
          f[j * 8 + e * 2 + 1] += __uint_as_float(uu[e] & 0xffff0000u);
        }
      }
    }
  } else {
    const float4* r0 = (const float4*)((const float*)base + (size_t)row * NN);
#pragma unroll
    for (int j = 0; j < 12; ++j) {
      float4 a = r0[lane + j * 64];
      f[j * 4 + 0] = a.x; f[j * 4 + 1] = a.y;
      f[j * 4 + 2] = a.z; f[j * 4 + 3] = a.w;
    }
  }
  if (outF8) {
    // bf path layout: f[j*8+e] = col (j*64+lane)*8 + e
    uint2* ob = (uint2*)(outF8 + (size_t)row * NN);
#pragma unroll
    for (int j = 0; j < 6; ++j) {
      uint2 w;
      w.x = pk4_f8(f[j * 8 + 0] * f8scale, f[j * 8 + 1] * f8scale,
                   f[j * 8 + 2] * f8scale, f[j * 8 + 3] * f8scale);
      w.y = pk4_f8(f[j * 8 + 4] * f8scale, f[j * 8 + 5] * f8scale,
                   f[j * 8 + 6] * f8scale, f[j * 8 + 7] * f8scale);
      ob[lane + j * 64] = w;
    }
  }
  // wave-wide OR / AND of keys -> constant-prefix skip
  unsigned bor = 0, band = 0xffffffffu;
#pragma unroll
  for (int r = 0; r < 48; ++r) {
    unsigned k = __float_as_uint(f[r]);
    bor |= k; band &= k;
  }
  for (int off = 32; off; off >>= 1) {
    bor |= (unsigned)__shfl_down((int)bor, off, 64);
    band &= (unsigned)__shfl_down((int)band, off, 64);
  }
  bor = (unsigned)__shfl((int)bor, 0, 64);
  band = (unsigned)__shfl((int)band, 0, 64);
  unsigned diff = bor ^ band;
  int hi = diff ? (31 - __clz(diff)) : 16;
  if (hi < 16) hi = 16;
  if (hi > 30) hi = 30;
  unsigned t = band & ~((hi < 31) ? ((2u << hi) - 1u) : 0xffffffffu);

  for (int b = hi; b >= 16; --b) {
    unsigned cand = t | (1u << b);
    int c = 0;
#pragma unroll
    for (int r = 0; r < 48; ++r) c += (__float_as_uint(f[r]) >= cand) ? 1 : 0;
    for (int off = 32; off; off >>= 1) c += __shfl_down(c, off, 64);
    c = __shfl(c, 0, 64);
    if (c >= 64) t = cand;
  }
  int basec = 0;
  int* oi = outIdx + (size_t)row * 128;
  float* ov = outVal + (size_t)row * 128;
#pragma unroll
  for (int r = 0; r < 48; ++r) {
    bool keep = __float_as_uint(f[r]) >= t;
    unsigned long long m = __ballot(keep);
    if (keep) {
      int pos = basec + __popcll(m & ((1ull << lane) - 1ull));
      if (pos < 128) {
        oi[pos] = bf ? ((r >> 3) * 512 + lane * 8 + (r & 7))
                     : ((r >> 2) * 256 + lane * 4 + (r & 3));
        ov[pos] = f[r] * descale;
      }
    }
    basec += __popcll(m);
  }
  if (lane == 0) outCnt[row] = basec < 128 ? basec : 128;
}

// ---------------------------------------------------------------------------
// prep: convert A -> fp8 (straight + transposed, x2^19) + fused y1/s1
// matvec partials. grid 2304 (48x48 tiles of 64x64). Conv-only: low VGPR
// (NEVER fuse high-VGPR roles here or into the GEMM -- R10 regression).
__global__ __launch_bounds__(256) void prep(
    const float* __restrict__ A, const float* __restrict__ vu,
    const float* __restrict__ vv, unsigned char* __restrict__ Af8,
    unsigned char* __restrict__ Atf8, float* __restrict__ y1,
    float* __restrict__ s1) {
  __shared__ float sh[64 * 65 + 512];
  const int bid = blockIdx.x;
  const int t = threadIdx.x;
  const int bx = (bid % 48) * 64, by = (bid / 48) * 64;
  const int rr = t >> 4;
  const int c4 = (t & 15) * 4;
  for (int it = 0; it < 4; ++it) {
    int r = rr + it * 16;
    float4 val = *(const float4*)(A + (size_t)(by + r) * NN + bx + c4);
    sh[r * 65 + c4] = val.x; sh[r * 65 + c4 + 1] = val.y;
    sh[r * 65 + c4 + 2] = val.z; sh[r * 65 + c4 + 3] = val.w;
    *(unsigned*)(Af8 + (size_t)(by + r) * NN + bx + c4) =
        pk4_f8(val.x * SCALE_A, val.y * SCALE_A, val.z * SCALE_A,
               val.w * SCALE_A);
  }
  __syncthreads();
  for (int it = 0; it < 4; ++it) {
    int c = (t >> 4) + it * 16;
    int r0 = (t & 15) * 4;
    *(unsigned*)(Atf8 + (size_t)(bx + c) * NN + by + r0) =
        pk4_f8(sh[r0 * 65 + c] * SCALE_A, sh[(r0 + 1) * 65 + c] * SCALE_A,
               sh[(r0 + 2) * 65 + c] * SCALE_A,
               sh[(r0 + 3) * 65 + c] * SCALE_A);
  }
  // fused matvec partials: y1[r] += A[r,:].v ; s1[c] += u.A[:,c]
  const int q = t >> 6;
  const int l = t & 63;
  float sy = 0.f, ss_ = 0.f;
  for (int i = 0; i < 16; ++i) {
    int c = q * 16 + i;
    sy += sh[l * 65 + c] * vv[bx + c];
    ss_ += vu[by + c] * sh[c * 65 + l];
  }
  float* red = sh + 64 * 65;
  red[q * 64 + l] = sy;
  red[256 + q * 64 + l] = ss_;
  __syncthreads();
  if (t < 64) {
    float v4 = red[t] + red[64 + t] + red[128 + t] + red[192 + t];
    atomAddF(&y1[by + t], v4);
  } else if (t < 128) {
    int cc = t - 64;
    float v4 = red[256 + cc] + red[256 + 64 + cc] + red[256 + 128 + cc] +
               red[256 + 192 + cc];
    atomAddF(&s1[bx + cc], v4);
  }
}

// ---------------------------------------------------------------------------
// fp8 GEMM via MX-scaled 32x32x64 f8f6f4 MFMA at unit scales (2x the
// non-scaled fp8 rate; bit-identical math: e4m3 inputs, fp32 accum).
// C(128x128 tile, bf16) = A(row-major fp8) * Bt(row-major fp8 = B^T), BK=64;
// split-K over blockIdx.z writing separate bf16 partial buffers.
// LDS per operand: 4 mtiles (32 rows x 64 k) x 2048 B;
// addr(r,k) = mt*2048 + (k/16)*512 + r*16 + k%16  (GLDS16-compatible).
__global__ __launch_bounds__(256) void gemm_f8(
    const unsigned char* __restrict__ Ag,
    const unsigned char* __restrict__ Btg,
    unsigned short* __restrict__ Cg, int kLen) {
  __shared__ __align__(16) unsigned char As[8192];
  __shared__ __align__(16) unsigned char Bs[8192];

  const int tid = threadIdx.x;
  const int wave = tid >> 6;
  const int lane = tid & 63;
  const int rowBase = blockIdx.y * 128;
  const int colBase = blockIdx.x * 128;
  const int wr = wave >> 1, wc = wave & 1;
  const int r32 = lane & 31, hh = lane >> 5;
  const int kStart = blockIdx.z * kLen;
  unsigned short* Cout = Cg + (size_t)blockIdx.z * NN * NN;

  f32x16 acc[2][2];
  for (int i = 0; i < 2; ++i)
    for (int j = 0; j < 2; ++j)
      for (int e = 0; e < 16; ++e) acc[i][j][e] = 0.f;

  // wave stages mtile `wave` of A and of B (32 rows x 64 k = 2 GLDS16 each)
  const unsigned char* aS =
      Ag + (size_t)(rowBase + wave * 32 + r32) * NN + hh * 16;
  const unsigned char* bS =
      Btg + (size_t)(colBase + wave * 32 + r32) * NN + hh * 16;
  unsigned char* aD = &As[wave * 2048];
  unsigned char* bD = &Bs[wave * 2048];

  for (int kt = kStart; kt < kStart + kLen; kt += 64) {
    GLDS16(aS + kt, aD);
    GLDS16(aS + kt + 32, aD + 1024);
    GLDS16(bS + kt, bD);
    GLDS16(bS + kt + 32, bD + 1024);
    __syncthreads();
    // lane (r32, hh) holds row r32, k in [hh*32, hh*32+32) of each mtile
    i32x8 af[2], bf[2];
    for (int i = 0; i < 2; ++i) {
      int base = (wr * 2 + i) * 2048 + hh * 1024 + r32 * 16;
      i32x4 lo = *(const i32x4*)&As[base];
      i32x4 hi2 = *(const i32x4*)&As[base + 512];
      af[i] = (i32x8){lo.x, lo.y, lo.z, lo.w, hi2.x, hi2.y, hi2.z, hi2.w};
    }
    for (int j = 0; j < 2; ++j) {
      int base = (wc * 2 + j) * 2048 + hh * 1024 + r32 * 16;
      i32x4 lo = *(const i32x4*)&Bs[base];
      i32x4 hi2 = *(const i32x4*)&Bs[base + 512];
      bf[j] = (i32x8){lo.x, lo.y, lo.z, lo.w, hi2.x, hi2.y, hi2.z, hi2.w};
    }
    for (int i = 0; i < 2; ++i)
      for (int j = 0; j < 2; ++j)
        acc[i][j] = __builtin_amdgcn_mfma_scale_f32_32x32x64_f8f6f4(
            af[i], bf[j], acc[i][j], 0, 0, 0, 127, 0, 127);
    __syncthreads();
  }
  // C/D 32x32 layout: col = lane&31, row = (reg&3) + 8*(reg>>2) + 4*(lane>>5)
  for (int i = 0; i < 2; ++i) {
    int rb = rowBase + wr * 64 + i * 32 + 4 * hh;
    for (int j = 0; j < 2; ++j) {
      int cc = colBase + wc * 64 + j * 32 + r32;
      for (int reg = 0; reg < 16; ++reg) {
        int rr = rb + (reg & 3) + 8 * (reg >> 2);
        Cout[(size_t)rr * NN + cc] = bf16bits(acc[i][j][reg]);
      }
    }
  }
}

// ---------------------------------------------------------------------------
// post1: [0,768)    topk(A2 bf16 partial-sum) + fp8 cast -> A2f8
//        [768,1536) topk(A fp32)  (layer 0)
//        [1536,2304) tvec = A.y1 (one wave per row)
__global__ __launch_bounds__(256) void post1(
    const unsigned short* __restrict__ C, int parts,
    const float* __restrict__ A, const float* __restrict__ y1,
    unsigned char* __restrict__ A2f8, int* __restrict__ cnts,
    int* __restrict__ tIdx, float* __restrict__ tVal,
    float* __restrict__ tvec) {
  const int bid = blockIdx.x;
  const int t = threadIdx.x;
  if (bid < 768) {
    int row = bid * 4 + (t >> 6);
    topk_row_dev(C, parts, 1, row, t & 63, DESCALE38, cnts + NN,
                 tIdx + (size_t)NN * 128, tVal + (size_t)NN * 128, A2f8,
                 F8SCALE2);
  } else if (bid < 1536) {
    int row = (bid - 768) * 4 + (t >> 6);
    topk_row_dev(A, 1, 0, row, t & 63, 1.0f, cnts, tIdx, tVal, nullptr, 0.f);
  } else {
    int row = (bid - 1536) * 4 + (t >> 6);
    int lane = t & 63;
    const float4* rp = (const float4*)(A + (size_t)row * NN);
    const float4* yp = (const float4*)y1;
    float s = 0.f;
#pragma unroll
    for (int j = 0; j < 12; ++j) {
      float4 a = rp[lane + j * 64];
      float4 y = yp[lane + j * 64];
      s += a.x * y.x + a.y * y.y + a.z * y.z + a.w * y.w;
    }
    for (int off = 32; off; off >>= 1) s += __shfl_down(s, off, 64);
    if (lane == 0) tvec[row] = s;
  }
}

// ---------------------------------------------------------------------------
// post2: [0,768) topk(A3 bf16 partial-sum); [768] w0..w3
__global__ __launch_bounds__(256) void post2(
    const unsigned short* __restrict__ C, int parts,
    const float* __restrict__ vu, const float* __restrict__ vv,
    const float* __restrict__ y1, const float* __restrict__ s1,
    const float* __restrict__ tvec, int* __restrict__ cnts,
    int* __restrict__ tIdx, float* __restrict__ tVal,
    float* __restrict__ wacc) {
  const int bid = blockIdx.x;
  const int t = threadIdx.x;
  if (bid < 768) {
    int row = bid * 4 + (t >> 6);
    topk_row_dev(C, parts, 1, row, t & 63, DESCALE38, cnts, tIdx, tVal,
                 nullptr, 0.f);
  } else {
    __shared__ float red4[4];
    float w0 = row_dot_f32(vu, vv, red4);  __syncthreads();
    float w1 = row_dot_f32(vu, y1, red4);  __syncthreads();
    float w2 = row_dot_f32(s1, y1, red4);  __syncthreads();
    float w3 = row_dot_f32(s1, tvec, red4);
    if (t == 0) { wacc[0] = w0; wacc[1] = w1; wacc[2] = w2; wacc[3] = w3; }
  }
}

// ---------------------------------------------------------------------------
static __device__ inline float ldE(const float* __restrict__ ue,
                                   const float* __restrict__ ie, int r, int d) {
  return r < NU ? ue[(size_t)r * DD + d] : ie[(size_t)(r - NU) * DD + d];
}

__global__ __launch_bounds__(128) void build_light(
    const float* __restrict__ uemb, const float* __restrict__ iemb,
    const float* __restrict__ uemb0, const float* __restrict__ iemb0,
    const float* __restrict__ wacc, const int* __restrict__ cnts,
    const int* __restrict__ tIdx, const float* __restrict__ tVal,
    float* __restrict__ lightOut) {
  float w0 = wacc[0], w1 = wacc[1], w2 = wacc[2], w3 = wacc[3];
  float ss = w0 + w1 + w2 + w3;
  w0 /= ss; w1 /= ss; w2 /= ss; w3 /= ss;
  float m = fmaxf(fmaxf(w0, w1), fmaxf(w2, w3));
  float e0 = expf(w0 - m), e1 = expf(w1 - m), e2 = expf(w2 - m),
        e3 = expf(w3 - m);
  float se = e0 + e1 + e2 + e3;
  float aw[4] = {e0 / se, e1 / se, e2 / se, e3 / se};
  float aw4 = GAMMA_F * (aw[1] + aw[2] + aw[3]);

  int row = blockIdx.x, d = threadIdx.x;
  float acc = aw[0] * ldE(uemb, iemb, row, d) +
              aw4 * ldE(uemb0, iemb0, row, d);
  __shared__ int sIdx[128];
  __shared__ float sVal[128];
  for (int l = 0; l < 3; ++l) {
    int c = cnts[l * NN + row];
    const int* ip = tIdx + ((size_t)l * NN + row) * 128;
    const float* vp = tVal + ((size_t)l * NN + row) * 128;
    __syncthreads();
    if (d < c) { sIdx[d] = ip[d]; sVal[d] = vp[d]; }
    __syncthreads();
    float al = aw[l + 1];
    float la = 0.f;
    for (int k = 0; k < c; ++k) la += sVal[k] * ldE(uemb, iemb, sIdx[k], d);
    acc += al * la;
  }
  lightOut[(size_t)row * DD + d] = acc;
}

__global__ __launch_bounds__(256) void out_dot(const int* __restrict__ users,
                                               const int* __restrict__ items,
                                               const float* __restrict__ lightOut,
                                               float* __restrict__ out) {
  int b = blockIdx.x * 4 + (threadIdx.x >> 6);
  int lane = threadIdx.x & 63;
  const float* up = lightOut + (size_t)users[b] * DD;
  const float* ip = lightOut + (size_t)(NU + items[b]) * DD;
  float s = up[lane] * ip[lane] + up[lane + 64] * ip[lane + 64];
  for (int off = 32; off; off >>= 1) s += __shfl_down(s, off, 64);
  if (lane == 0) out[b] = s;
}

// ---------------------------------------------------------------------------
extern "C" void kernel_launch(void* const* d_in, const int* in_sizes, int n_in,
                              void* d_out, int out_size, void* d_ws,
                              size_t ws_size, hipStream_t stream) {
  const int* users = (const int*)d_in[0];
  const int* items = (const int*)d_in[1];
  const float* A = (const float*)d_in[2];
  const float* uemb = (const float*)d_in[3];
  const float* iemb = (const float*)d_in[4];
  const float* uemb0 = (const float*)d_in[5];
  const float* iemb0 = (const float*)d_in[6];
  const float* vu = (const float*)d_in[7];
  const float* vv = (const float*)d_in[8];
  float* out = (float*)d_out;

  char* ws = (char*)d_ws;
  size_t off = 0;
  auto alloc = [&](size_t bytes) -> void* {
    void* p = ws + off;
    off += (bytes + 255) & ~(size_t)255;
    return p;
  };
  unsigned char* Af8 = (unsigned char*)alloc((size_t)NN * NN);
  unsigned char* Atf8 = (unsigned char*)alloc((size_t)NN * NN);
  unsigned char* A2f8 = (unsigned char*)alloc((size_t)NN * NN);
  float* y1 = (float*)alloc((size_t)NN * 4);   // contiguous with s1
  float* s1 = (float*)alloc((size_t)NN * 4);
  float* tvec = (float*)alloc((size_t)NN * 4);
  float* wacc = (float*)alloc(256);
  int* cnts = (int*)alloc((size_t)3 * NN * 4);
  int* tIdx = (int*)alloc((size_t)3 * NN * 128 * 4);
  float* tVal = (float*)alloc((size_t)3 * NN * 128 * 4);
  float* lightOut = (float*)alloc((size_t)NN * DD * 4);

  const size_t cBytes = (size_t)NN * NN * 2;  // bf16 partials
  int kParts = (ws_size >= off + 2 * cBytes + 512) ? 2 : 1;
  unsigned short* C = (unsigned short*)alloc((size_t)kParts * cBytes);
  const int kLen = NN / kParts;

  // 1) zero y1/s1 (contiguous 2*NN floats)
  hipMemsetAsync(y1, 0, (size_t)2 * NN * 4, stream);
  // 2) prep: A -> fp8 (straight+transposed) + y1/s1 partials
  prep<<<2304, 256, 0, stream>>>(A, vu, vv, Af8, Atf8, y1, s1);
  // 3) A2 = A*A (MX fp8 MFMA BK=64, bf16 partials x2)
  gemm_f8<<<dim3(24, 24, kParts), 256, 0, stream>>>(Af8, Atf8, C, kLen);
  // 4) post1: topk(A2)+fp8 cast | topk(A) | tvec = A.y1
  post1<<<2304, 256, 0, stream>>>(C, kParts, A, y1, A2f8, cnts, tIdx, tVal,
                                  tvec);
  // 5) A3 = A2*A (overwrite partials)
  gemm_f8<<<dim3(24, 24, kParts), 256, 0, stream>>>(A2f8, Atf8, C, kLen);
  // 6) post2: topk(A3) | w0..w3
  post2<<<769, 256, 0, stream>>>(C, kParts, vu, vv, y1, s1, tvec,
                                 cnts + 2 * NN, tIdx + (size_t)2 * NN * 128,
                                 tVal + (size_t)2 * NN * 128, wacc);
  // 7) light_out (attn softmax inlined)
  build_light<<<NN, 128, 0, stream>>>(uemb, iemb, uemb0, iemb0, wacc, cnts,
                                      tIdx, tVal, lightOut);
  // 8) gather dots
  out_dot<<<BB / 4, 256, 0, stream>>>(users, items, lightOut, out);
}

// Round 13
// 329.700 us; speedup vs baseline: 1.5498x; 1.0305x over previous
//
#include <hip/hip_runtime.h>
#include <hip/hip_fp8.h>
#include <math.h>

#define NN 3072
#define NU 1024
#define NI 2048
#define DD 128
#define BB 8192
#define GAMMA_F 0.2f

#define SCALE_A 524288.0f                // 2^19
#define F8SCALE2 1.9073486328125e-06f    // 2^-19  (C*2^38 -> A2*2^19 for fp8)
#define DESCALE38 3.637978807091713e-12f // 2^-38  (C -> true A^k values)

// packed fp8 layout: [k/64][row][k%64]; one k-block = NN rows x 64 B
#define KBLK ((size_t)NN * 64)

typedef __attribute__((ext_vector_type(4))) float f32x4;
typedef __attribute__((ext_vector_type(16))) float f32x16;
typedef __attribute__((ext_vector_type(4))) int i32x4;
typedef __attribute__((ext_vector_type(8))) int i32x8;

static __device__ inline unsigned short bf16bits(float x) {
  union { unsigned u; float f; } cv;
  cv.f = x;
  unsigned r = cv.u + 0x7fff + ((cv.u >> 16) & 1);  // RNE
  return (unsigned short)(r >> 16);
}

// pack 4 floats -> 4 fp8 e4m3 (OCP) bytes
static __device__ inline unsigned pk4_f8(float a, float b, float c, float d) {
#if defined(__has_builtin)
#if __has_builtin(__builtin_amdgcn_cvt_pk_fp8_f32)
  int p = __builtin_amdgcn_cvt_pk_fp8_f32(a, b, 0, false);
  p = __builtin_amdgcn_cvt_pk_fp8_f32(c, d, p, true);
  return (unsigned)p;
#else
  return (unsigned)__hip_fp8_e4m3(a).__x | ((unsigned)__hip_fp8_e4m3(b).__x << 8) |
         ((unsigned)__hip_fp8_e4m3(c).__x << 16) |
         ((unsigned)__hip_fp8_e4m3(d).__x << 24);
#endif
#else
  return (unsigned)__hip_fp8_e4m3(a).__x | ((unsigned)__hip_fp8_e4m3(b).__x << 8) |
         ((unsigned)__hip_fp8_e4m3(c).__x << 16) |
         ((unsigned)__hip_fp8_e4m3(d).__x << 24);
#endif
}

static __device__ inline void atomAddF(float* p, float v) {
#if defined(__has_builtin)
#if __has_builtin(__builtin_amdgcn_global_atomic_fadd_f32)
  __builtin_amdgcn_global_atomic_fadd_f32(
      (__attribute__((address_space(1))) float*)p, v);
#else
  unsafeAtomicAdd(p, v);
#endif
#else
  unsafeAtomicAdd(p, v);
#endif
}

static __device__ inline float block_sum(float s, float* red4) {
  int tid = threadIdx.x;
  for (int off = 32; off; off >>= 1) s += __shfl_down(s, off, 64);
  if ((tid & 63) == 0) red4[tid >> 6] = s;
  __syncthreads();
  return red4[0] + red4[1] + red4[2] + red4[3];
}

static __device__ inline float row_dot_f32(const float* __restrict__ a,
                                           const float* __restrict__ b,
                                           float* red4) {
  const float4* ap = (const float4*)a;
  const float4* bp = (const float4*)b;
  float s = 0.f;
  for (int j = threadIdx.x; j < NN / 4; j += 256) {
    float4 x = ap[j], y = bp[j];
    s += x.x * y.x + x.y * y.y + x.z * y.z + x.w * y.w;
  }
  return block_sum(s, red4);
}

// ---------------------------------------------------------------------------
// Per-row top-64 via radix select on bits [30..16] with wave OR/AND
// prefix-skip; one wave per row. bf=1: bf16 partials. bf=0: fp32 matrix.
// outF8: fused fp8 cast written in PACKED k-blocked layout.
static __device__ void topk_row_dev(const void* __restrict__ base, int parts,
                                    int bf, int row, int lane, float descale,
                                    int* __restrict__ outCnt,
                                    int* __restrict__ outIdx,
                                    float* __restrict__ outVal,
                                    unsigned char* __restrict__ outF8,
                                    float f8scale) {
  float f[48];
  if (bf) {
    const unsigned short* b0 = (const unsigned short*)base;
    const uint4* r0 = (const uint4*)(b0 + (size_t)row * NN);
#pragma unroll
    for (int j = 0; j < 6; ++j) {
      uint4 q = r0[lane + j * 64];
      unsigned uu[4] = {q.x, q.y, q.z, q.w};
#pragma unroll
      for (int e = 0; e < 4; ++e) {
        f[j * 8 + e * 2] = __uint_as_float(uu[e] << 16);
        f[j * 8 + e * 2 + 1] = __uint_as_float(uu[e] & 0xffff0000u);
      }
    }
    for (int p = 1; p < parts; ++p) {
      const uint4* rp =
          (const uint4*)(b0 + (size_t)p * NN * NN + (size_t)row * NN);
#pragma unroll
      for (int j = 0; j < 6; ++j) {
        uint4 q = rp[lane + j * 64];
        unsigned uu[4] = {q.x, q.y, q.z, q.w};
#pragma unroll
        for (int e = 0; e < 4; ++e) {
          f[j * 8 + e * 2] += __uint_as_float(uu[e] << 16);
          f[j * 8 + e * 2 + 1] += __uint_as_float(uu[e] & 0xffff0000u);
        }
      }
    }
  } else {
    const float4* r0 = (const float4*)((const float*)base + (size_t)row * NN);
#pragma unroll
    for (int j = 0; j < 12; ++j) {
      float4 a = r0[lane + j * 64];
      f[j * 4 + 0] = a.x; f[j * 4 + 1] = a.y;
      f[j * 4 + 2] = a.z; f[j * 4 + 3] = a.w;
    }
  }
  if (outF8) {
    // f[j*8+e] = col k0+e, k0 = (j*64+lane)*8; packed addr =
    // (k0>>6)*KBLK + row*64 + (k0&63)
#pragma unroll
    for (int j = 0; j < 6; ++j) {
      uint2 w;
      w.x = pk4_f8(f[j * 8 + 0] * f8scale, f[j * 8 + 1] * f8scale,
                   f[j * 8 + 2] * f8scale, f[j * 8 + 3] * f8scale);
      w.y = pk4_f8(f[j * 8 + 4] * f8scale, f[j * 8 + 5] * f8scale,
                   f[j * 8 + 6] * f8scale, f[j * 8 + 7] * f8scale);
      size_t addr = (size_t)(j * 8 + (lane >> 3)) * KBLK +
                    (size_t)row * 64 + (lane & 7) * 8;
      *(uint2*)(outF8 + addr) = w;
    }
  }
  unsigned bor = 0, band = 0xffffffffu;
#pragma unroll
  for (int r = 0; r < 48; ++r) {
    unsigned k = __float_as_uint(f[r]);
    bor |= k; band &= k;
  }
  for (int off = 32; off; off >>= 1) {
    bor |= (unsigned)__shfl_down((int)bor, off, 64);
    band &= (unsigned)__shfl_down((int)band, off, 64);
  }
  bor = (unsigned)__shfl((int)bor, 0, 64);
  band = (unsigned)__shfl((int)band, 0, 64);
  unsigned diff = bor ^ band;
  int hi = diff ? (31 - __clz(diff)) : 16;
  if (hi < 16) hi = 16;
  if (hi > 30) hi = 30;
  unsigned t = band & ~((hi < 31) ? ((2u << hi) - 1u) : 0xffffffffu);

  for (int b = hi; b >= 16; --b) {
    unsigned cand = t | (1u << b);
    int c = 0;
#pragma unroll
    for (int r = 0; r < 48; ++r) c += (__float_as_uint(f[r]) >= cand) ? 1 : 0;
    for (int off = 32; off; off >>= 1) c += __shfl_down(c, off, 64);
    c = __shfl(c, 0, 64);
    if (c >= 64) t = cand;
  }
  int basec = 0;
  int* oi = outIdx + (size_t)row * 128;
  float* ov = outVal + (size_t)row * 128;
#pragma unroll
  for (int r = 0; r < 48; ++r) {
    bool keep = __float_as_uint(f[r]) >= t;
    unsigned long long m = __ballot(keep);
    if (keep) {
      int pos = basec + __popcll(m & ((1ull << lane) - 1ull));
      if (pos < 128) {
        oi[pos] = bf ? ((r >> 3) * 512 + lane * 8 + (r & 7))
                     : ((r >> 2) * 256 + lane * 4 + (r & 3));
        ov[pos] = f[r] * descale;
      }
    }
    basec += __popcll(m);
  }
  if (lane == 0) outCnt[row] = basec < 128 ? basec : 128;
}

// ---------------------------------------------------------------------------
// prep: A -> fp8 PACKED (straight + transposed, x2^19) + fused y1/s1 matvec
// partials. grid 2304 (48x48 tiles of 64x64).
__global__ __launch_bounds__(256) void prep(
    const float* __restrict__ A, const float* __restrict__ vu,
    const float* __restrict__ vv, unsigned char* __restrict__ Af8,
    unsigned char* __restrict__ Atf8, float* __restrict__ y1,
    float* __restrict__ s1) {
  __shared__ float sh[64 * 65 + 512];
  const int bid = blockIdx.x;
  const int t = threadIdx.x;
  const int bx = (bid % 48) * 64, by = (bid / 48) * 64;
  const int rr = t >> 4;
  const int c4 = (t & 15) * 4;
  for (int it = 0; it < 4; ++it) {
    int r = rr + it * 16;
    float4 val = *(const float4*)(A + (size_t)(by + r) * NN + bx + c4);
    sh[r * 65 + c4] = val.x; sh[r * 65 + c4 + 1] = val.y;
    sh[r * 65 + c4 + 2] = val.z; sh[r * 65 + c4 + 3] = val.w;
  }
  __syncthreads();
  {
    // straight packed: thread writes 16 fp8 of row (t>>2), k-chunk (t&3)
    int row = t >> 2, ch = t & 3;
    const float* sp = &sh[row * 65 + ch * 16];
    uint4 w;
    w.x = pk4_f8(sp[0] * SCALE_A, sp[1] * SCALE_A, sp[2] * SCALE_A,
                 sp[3] * SCALE_A);
    w.y = pk4_f8(sp[4] * SCALE_A, sp[5] * SCALE_A, sp[6] * SCALE_A,
                 sp[7] * SCALE_A);
    w.z = pk4_f8(sp[8] * SCALE_A, sp[9] * SCALE_A, sp[10] * SCALE_A,
                 sp[11] * SCALE_A);
    w.w = pk4_f8(sp[12] * SCALE_A, sp[13] * SCALE_A, sp[14] * SCALE_A,
                 sp[15] * SCALE_A);
    *(uint4*)(Af8 + (size_t)(bx >> 6) * KBLK + (size_t)(by + row) * 64 +
              ch * 16) = w;
  }
  {
    // transposed packed: thread writes At row bx+(t>>2), k-chunk (t&3)
    int c = t >> 2, ch = t & 3;
    float v[16];
#pragma unroll
    for (int e = 0; e < 16; ++e) v[e] = sh[(ch * 16 + e) * 65 + c];
    uint4 w;
    w.x = pk4_f8(v[0] * SCALE_A, v[1] * SCALE_A, v[2] * SCALE_A,
                 v[3] * SCALE_A);
    w.y = pk4_f8(v[4] * SCALE_A, v[5] * SCALE_A, v[6] * SCALE_A,
                 v[7] * SCALE_A);
    w.z = pk4_f8(v[8] * SCALE_A, v[9] * SCALE_A, v[10] * SCALE_A,
                 v[11] * SCALE_A);
    w.w = pk4_f8(v[12] * SCALE_A, v[13] * SCALE_A, v[14] * SCALE_A,
                 v[15] * SCALE_A);
    *(uint4*)(Atf8 + (size_t)(by >> 6) * KBLK + (size_t)(bx + c) * 64 +
              ch * 16) = w;
  }
  // fused matvec partials: y1[r] += A[r,:].v ; s1[c] += u.A[:,c]
  const int q = t >> 6;
  const int l = t & 63;
  float sy = 0.f, ss_ = 0.f;
  for (int i = 0; i < 16; ++i) {
    int c = q * 16 + i;
    sy += sh[l * 65 + c] * vv[bx + c];
    ss_ += vu[by + c] * sh[c * 65 + l];
  }
  float* red = sh + 64 * 65;
  red[q * 64 + l] = sy;
  red[256 + q * 64 + l] = ss_;
  __syncthreads();
  if (t < 64) {
    float v4 = red[t] + red[64 + t] + red[128 + t] + red[192 + t];
    atomAddF(&y1[by + t], v4);
  } else if (t < 128) {
    int cc = t - 64;
    float v4 = red[256 + cc] + red[256 + 64 + cc] + red[256 + 128 + cc] +
               red[256 + 192 + cc];
    atomAddF(&s1[bx + cc], v4);
  }
}

// ---------------------------------------------------------------------------
// LDS-free fp8 GEMM via MX-scaled 32x32x64 MFMA at unit scales.
// Operands in PACKED k-blocked layout; fragments loaded straight from global
// into registers (2x dwordx4 per fragment), register double-buffered so the
// compiler pipelines with vmcnt(N>0). No barriers in the K-loop.
static __device__ inline i32x8 ldfrag(const unsigned char* p) {
  i32x4 lo = *(const i32x4*)p;
  i32x4 hi = *(const i32x4*)(p + 16);
  return (i32x8){lo.x, lo.y, lo.z, lo.w, hi.x, hi.y, hi.z, hi.w};
}

__global__ __launch_bounds__(256) void gemm_f8(
    const unsigned char* __restrict__ Ag,
    const unsigned char* __restrict__ Btg,
    unsigned short* __restrict__ Cg, int kLen) {
  const int tid = threadIdx.x;
  const int wave = tid >> 6;
  const int lane = tid & 63;
  const int rowBase = blockIdx.y * 128;
  const int colBase = blockIdx.x * 128;
  const int wr = wave >> 1, wc = wave & 1;
  const int r32 = lane & 31, hh = lane >> 5;
  const int kStart = blockIdx.z * kLen;
  unsigned short* Cout = Cg + (size_t)blockIdx.z * NN * NN;

  f32x16 acc[2][2];
  for (int i = 0; i < 2; ++i)
    for (int j = 0; j < 2; ++j)
      for (int e = 0; e < 16; ++e) acc[i][j][e] = 0.f;

  const unsigned char* aP0 = Ag + (size_t)(kStart >> 6) * KBLK +
                             (size_t)(rowBase + (wr * 2) * 32 + r32) * 64 +
                             hh * 32;
  const unsigned char* aP1 = aP0 + 32 * 64;
  const unsigned char* bP0 = Btg + (size_t)(kStart >> 6) * KBLK +
                             (size_t)(colBase + (wc * 2) * 32 + r32) * 64 +
                             hh * 32;
  const unsigned char* bP1 = bP0 + 32 * 64;

  const int nIter = kLen >> 6;
  i32x8 a0 = ldfrag(aP0), a1 = ldfrag(aP1);
  i32x8 b0 = ldfrag(bP0), b1 = ldfrag(bP1);
  for (int it = 0; it < nIter - 1; ++it) {
    aP0 += KBLK; aP1 += KBLK; bP0 += KBLK; bP1 += KBLK;
    i32x8 na0 = ldfrag(aP0), na1 = ldfrag(aP1);
    i32x8 nb0 = ldfrag(bP0), nb1 = ldfrag(bP1);
    acc[0][0] = __builtin_amdgcn_mfma_scale_f32_32x32x64_f8f6f4(
        a0, b0, acc[0][0], 0, 0, 0, 127, 0, 127);
    acc[0][1] = __builtin_amdgcn_mfma_scale_f32_32x32x64_f8f6f4(
        a0, b1, acc[0][1], 0, 0, 0, 127, 0, 127);
    acc[1][0] = __builtin_amdgcn_mfma_scale_f32_32x32x64_f8f6f4(
        a1, b0, acc[1][0], 0, 0, 0, 127, 0, 127);
    acc[1][1] = __builtin_amdgcn_mfma_scale_f32_32x32x64_f8f6f4(
        a1, b1, acc[1][1], 0, 0, 0, 127, 0, 127);
    a0 = na0; a1 = na1; b0 = nb0; b1 = nb1;
  }
  acc[0][0] = __builtin_amdgcn_mfma_scale_f32_32x32x64_f8f6f4(
      a0, b0, acc[0][0], 0, 0, 0, 127, 0, 127);
  acc[0][1] = __builtin_amdgcn_mfma_scale_f32_32x32x64_f8f6f4(
      a0, b1, acc[0][1], 0, 0, 0, 127, 0, 127);
  acc[1][0] = __builtin_amdgcn_mfma_scale_f32_32x32x64_f8f6f4(
      a1, b0, acc[1][0], 0, 0, 0, 127, 0, 127);
  acc[1][1] = __builtin_amdgcn_mfma_scale_f32_32x32x64_f8f6f4(
      a1, b1, acc[1][1], 0, 0, 0, 127, 0, 127);

  // C/D 32x32 layout: col = lane&31, row = (reg&3) + 8*(reg>>2) + 4*(lane>>5)
  for (int i = 0; i < 2; ++i) {
    int rb = rowBase + wr * 64 + i * 32 + 4 * hh;
    for (int j = 0; j < 2; ++j) {
      int cc = colBase + wc * 64 + j * 32 + r32;
      for (int reg = 0; reg < 16; ++reg) {
        int rr = rb + (reg & 3) + 8 * (reg >> 2);
        Cout[(size_t)rr * NN + cc] = bf16bits(acc[i][j][reg]);
      }
    }
  }
}

// ---------------------------------------------------------------------------
// post1: [0,768)    topk(A2 bf16 partial-sum) + packed fp8 cast -> A2f8
//        [768,1536) topk(A fp32)  (layer 0)
//        [1536,2304) tvec = A.y1 (one wave per row)
__global__ __launch_bounds__(256) void post1(
    const unsigned short* __restrict__ C, int parts,
    const float* __restrict__ A, const float* __restrict__ y1,
    unsigned char* __restrict__ A2f8, int* __restrict__ cnts,
    int* __restrict__ tIdx, float* __restrict__ tVal,
    float* __restrict__ tvec) {
  const int bid = blockIdx.x;
  const int t = threadIdx.x;
  if (bid < 768) {
    int row = bid * 4 + (t >> 6);
    topk_row_dev(C, parts, 1, row, t & 63, DESCALE38, cnts + NN,
                 tIdx + (size_t)NN * 128, tVal + (size_t)NN * 128, A2f8,
                 F8SCALE2);
  } else if (bid < 1536) {
    int row = (bid - 768) * 4 + (t >> 6);
    topk_row_dev(A, 1, 0, row, t & 63, 1.0f, cnts, tIdx, tVal, nullptr, 0.f);
  } else {
    int row = (bid - 1536) * 4 + (t >> 6);
    int lane = t & 63;
    const float4* rp = (const float4*)(A + (size_t)row * NN);
    const float4* yp = (const float4*)y1;
    float s = 0.f;
#pragma unroll
    for (int j = 0; j < 12; ++j) {
      float4 a = rp[lane + j * 64];
      float4 y = yp[lane + j * 64];
      s += a.x * y.x + a.y * y.y + a.z * y.z + a.w * y.w;
    }
    for (int off = 32; off; off >>= 1) s += __shfl_down(s, off, 64);
    if (lane == 0) tvec[row] = s;
  }
}

// ---------------------------------------------------------------------------
// post2: [0,768) topk(A3 bf16 partial-sum); [768] w0..w3
__global__ __launch_bounds__(256) void post2(
    const unsigned short* __restrict__ C, int parts,
    const float* __restrict__ vu, const float* __restrict__ vv,
    const float* __restrict__ y1, const float* __restrict__ s1,
    const float* __restrict__ tvec, int* __restrict__ cnts,
    int* __restrict__ tIdx, float* __restrict__ tVal,
    float* __restrict__ wacc) {
  const int bid = blockIdx.x;
  const int t = threadIdx.x;
  if (bid < 768) {
    int row = bid * 4 + (t >> 6);
    topk_row_dev(C, parts, 1, row, t & 63, DESCALE38, cnts, tIdx, tVal,
                 nullptr, 0.f);
  } else {
    __shared__ float red4[4];
    float w0 = row_dot_f32(vu, vv, red4);  __syncthreads();
    float w1 = row_dot_f32(vu, y1, red4);  __syncthreads();
    float w2 = row_dot_f32(s1, y1, red4);  __syncthreads();
    float w3 = row_dot_f32(s1, tvec, red4);
    if (t == 0) { wacc[0] = w0; wacc[1] = w1; wacc[2] = w2; wacc[3] = w3; }
  }
}

// ---------------------------------------------------------------------------
static __device__ inline float ldE(const float* __restrict__ ue,
                                   const float* __restrict__ ie, int r, int d) {
  return r < NU ? ue[(size_t)r * DD + d] : ie[(size_t)(r - NU) * DD + d];
}

__global__ __launch_bounds__(128) void build_light(
    const float* __restrict__ uemb, const float* __restrict__ iemb,
    const float* __restrict__ uemb0, const float* __restrict__ iemb0,
    const float* __restrict__ wacc, const int* __restrict__ cnts,
    const int* __restrict__ tIdx, const float* __restrict__ tVal,
    float* __restrict__ lightOut) {
  float w0 = wacc[0], w1 = wacc[1], w2 = wacc[2], w3 = wacc[3];
  float ss = w0 + w1 + w2 + w3;
  w0 /= ss; w1 /= ss; w2 /= ss; w3 /= ss;
  float m = fmaxf(fmaxf(w0, w1), fmaxf(w2, w3));
  float e0 = expf(w0 - m), e1 = expf(w1 - m), e2 = expf(w2 - m),
        e3 = expf(w3 - m);
  float se = e0 + e1 + e2 + e3;
  float aw[4] = {e0 / se, e1 / se, e2 / se, e3 / se};
  float aw4 = GAMMA_F * (aw[1] + aw[2] + aw[3]);

  int row = blockIdx.x, d = threadIdx.x;
  float acc = aw[0] * ldE(uemb, iemb, row, d) +
              aw4 * ldE(uemb0, iemb0, row, d);
  __shared__ int sIdx[128];
  __shared__ float sVal[128];
  for (int l = 0; l < 3; ++l) {
    int c = cnts[l * NN + row];
    const int* ip = tIdx + ((size_t)l * NN + row) * 128;
    const float* vp = tVal + ((size_t)l * NN + row) * 128;
    __syncthreads();
    if (d < c) { sIdx[d] = ip[d]; sVal[d] = vp[d]; }
    __syncthreads();
    float al = aw[l + 1];
    float la = 0.f;
    for (int k = 0; k < c; ++k) la += sVal[k] * ldE(uemb, iemb, sIdx[k], d);
    acc += al * la;
  }
  lightOut[(size_t)row * DD + d] = acc;
}

__global__ __launch_bounds__(256) void out_dot(const int* __restrict__ users,
                                               const int* __restrict__ items,
                                               const float* __restrict__ lightOut,
                                               float* __restrict__ out) {
  int b = blockIdx.x * 4 + (threadIdx.x >> 6);
  int lane = threadIdx.x & 63;
  const float* up = lightOut + (size_t)users[b] * DD;
  const float* ip = lightOut + (size_t)(NU + items[b]) * DD;
  float s = up[lane] * ip[lane] + up[lane + 64] * ip[lane + 64];
  for (int off = 32; off; off >>= 1) s += __shfl_down(s, off, 64);
  if (lane == 0) out[b] = s;
}

// ---------------------------------------------------------------------------
extern "C" void kernel_launch(void* const* d_in, const int* in_sizes, int n_in,
                              void* d_out, int out_size, void* d_ws,
                              size_t ws_size, hipStream_t stream) {
  const int* users = (const int*)d_in[0];
  const int* items = (const int*)d_in[1];
  const float* A = (const float*)d_in[2];
  const float* uemb = (const float*)d_in[3];
  const float* iemb = (const float*)d_in[4];
  const float* uemb0 = (const float*)d_in[5];
  const float* iemb0 = (const float*)d_in[6];
  const float* vu = (const float*)d_in[7];
  const float* vv = (const float*)d_in[8];
  float* out = (float*)d_out;

  char* ws = (char*)d_ws;
  size_t off = 0;
  auto alloc = [&](size_t bytes) -> void* {
    void* p = ws + off;
    off += (bytes + 255) & ~(size_t)255;
    return p;
  };
  unsigned char* Af8 = (unsigned char*)alloc((size_t)NN * NN);
  unsigned char* Atf8 = (unsigned char*)alloc((size_t)NN * NN);
  unsigned char* A2f8 = (unsigned char*)alloc((size_t)NN * NN);
  float* y1 = (float*)alloc((size_t)NN * 4);   // contiguous with s1
  float* s1 = (float*)alloc((size_t)NN * 4);
  float* tvec = (float*)alloc((size_t)NN * 4);
  float* wacc = (float*)alloc(256);
  int* cnts = (int*)alloc((size_t)3 * NN * 4);
  int* tIdx = (int*)alloc((size_t)3 * NN * 128 * 4);
  float* tVal = (float*)alloc((size_t)3 * NN * 128 * 4);
  float* lightOut = (float*)alloc((size_t)NN * DD * 4);

  const size_t cBytes = (size_t)NN * NN * 2;  // bf16 partials
  int kParts = (ws_size >= off + 2 * cBytes + 512) ? 2 : 1;
  unsigned short* C = (unsigned short*)alloc((size_t)kParts * cBytes);
  const int kLen = NN / kParts;

  // 1) zero y1/s1 (contiguous 2*NN floats)
  hipMemsetAsync(y1, 0, (size_t)2 * NN * 4, stream);
  // 2) prep: A -> packed fp8 (straight+transposed) + y1/s1 partials
  prep<<<2304, 256, 0, stream>>>(A, vu, vv, Af8, Atf8, y1, s1);
  // 3) A2 = A*A (LDS-free MX fp8 MFMA, bf16 partials x2)
  gemm_f8<<<dim3(24, 24, kParts), 256, 0, stream>>>(Af8, Atf8, C, kLen);
  // 4) post1: topk(A2)+packed fp8 cast | topk(A) | tvec = A.y1
  post1<<<2304, 256, 0, stream>>>(C, kParts, A, y1, A2f8, cnts, tIdx, tVal,
                                  tvec);
  // 5) A3 = A2*A (overwrite partials)
  gemm_f8<<<dim3(24, 24, kParts), 256, 0, stream>>>(A2f8, Atf8, C, kLen);
  // 6) post2: topk(A3) | w0..w3
  post2<<<769, 256, 0, stream>>>(C, kParts, vu, vv, y1, s1, tvec,
                                 cnts + 2 * NN, tIdx + (size_t)2 * NN * 128,
                                 tVal + (size_t)2 * NN * 128, wacc);
  // 7) light_out (attn softmax inlined)
  build_light<<<NN, 128, 0, stream>>>(uemb, iemb, uemb0, iemb0, wacc, cnts,
                                      tIdx, tVal, lightOut);
  // 8) gather dots
  out_dot<<<BB / 4, 256, 0, stream>>>(users, items, lightOut, out);
}

// Round 14
// 313.151 us; speedup vs baseline: 1.6317x; 1.0528x over previous
//
#include <hip/hip_runtime.h>
#include <hip/hip_fp8.h>
#include <math.h>

#define NN 3072
#define NU 1024
#define NI 2048
#define DD 128
#define BB 8192
#define GAMMA_F 0.2f

#define SCALE_A 524288.0f                // 2^19
#define F8SCALE2 1.9073486328125e-06f    // 2^-19  (C*2^38 -> A2*2^19 for fp8)
#define DESCALE38 3.637978807091713e-12f // 2^-38  (C -> true A^k values)

// packed fp8 layout: [k/64][row][k%64]; one k-block = NN rows x 64 B
#define KBLK ((size_t)NN * 64)

typedef __attribute__((ext_vector_type(4))) float f32x4;
typedef __attribute__((ext_vector_type(16))) float f32x16;
typedef __attribute__((ext_vector_type(4))) int i32x4;
typedef __attribute__((ext_vector_type(8))) int i32x8;

static __device__ inline unsigned short bf16bits(float x) {
  union { unsigned u; float f; } cv;
  cv.f = x;
  unsigned r = cv.u + 0x7fff + ((cv.u >> 16) & 1);  // RNE
  return (unsigned short)(r >> 16);
}

// pack 4 floats -> 4 fp8 e4m3 (OCP) bytes
static __device__ inline unsigned pk4_f8(float a, float b, float c, float d) {
#if defined(__has_builtin)
#if __has_builtin(__builtin_amdgcn_cvt_pk_fp8_f32)
  int p = __builtin_amdgcn_cvt_pk_fp8_f32(a, b, 0, false);
  p = __builtin_amdgcn_cvt_pk_fp8_f32(c, d, p, true);
  return (unsigned)p;
#else
  return (unsigned)__hip_fp8_e4m3(a).__x | ((unsigned)__hip_fp8_e4m3(b).__x << 8) |
         ((unsigned)__hip_fp8_e4m3(c).__x << 16) |
         ((unsigned)__hip_fp8_e4m3(d).__x << 24);
#endif
#else
  return (unsigned)__hip_fp8_e4m3(a).__x | ((unsigned)__hip_fp8_e4m3(b).__x << 8) |
         ((unsigned)__hip_fp8_e4m3(c).__x << 16) |
         ((unsigned)__hip_fp8_e4m3(d).__x << 24);
#endif
}

static __device__ inline void atomAddF(float* p, float v) {
#if defined(__has_builtin)
#if __has_builtin(__builtin_amdgcn_global_atomic_fadd_f32)
  __builtin_amdgcn_global_atomic_fadd_f32(
      (__attribute__((address_space(1))) float*)p, v);
#else
  unsafeAtomicAdd(p, v);
#endif
#else
  unsafeAtomicAdd(p, v);
#endif
}

static __device__ inline float block_sum(float s, float* red4) {
  int tid = threadIdx.x;
  for (int off = 32; off; off >>= 1) s += __shfl_down(s, off, 64);
  if ((tid & 63) == 0) red4[tid >> 6] = s;
  __syncthreads();
  return red4[0] + red4[1] + red4[2] + red4[3];
}

static __device__ inline float row_dot_f32(const float* __restrict__ a,
                                           const float* __restrict__ b,
                                           float* red4) {
  const float4* ap = (const float4*)a;
  const float4* bp = (const float4*)b;
  float s = 0.f;
  for (int j = threadIdx.x; j < NN / 4; j += 256) {
    float4 x = ap[j], y = bp[j];
    s += x.x * y.x + x.y * y.y + x.z * y.z + x.w * y.w;
  }
  return block_sum(s, red4);
}

// ---------------------------------------------------------------------------
// topk loaders: fill f[48] with this row's values (one wave, 48 vals/lane).
static __device__ inline void load48_bf(const unsigned short* __restrict__ b0,
                                        int parts, int row, int lane,
                                        float* f) {
  const uint4* r0 = (const uint4*)(b0 + (size_t)row * NN);
#pragma unroll
  for (int j = 0; j < 6; ++j) {
    uint4 q = r0[lane + j * 64];
    unsigned uu[4] = {q.x, q.y, q.z, q.w};
#pragma unroll
    for (int e = 0; e < 4; ++e) {
      f[j * 8 + e * 2] = __uint_as_float(uu[e] << 16);
      f[j * 8 + e * 2 + 1] = __uint_as_float(uu[e] & 0xffff0000u);
    }
  }
  for (int p = 1; p < parts; ++p) {
    const uint4* rp = (const uint4*)(b0 + (size_t)p * NN * NN + (size_t)row * NN);
#pragma unroll
    for (int j = 0; j < 6; ++j) {
      uint4 q = rp[lane + j * 64];
      unsigned uu[4] = {q.x, q.y, q.z, q.w};
#pragma unroll
      for (int e = 0; e < 4; ++e) {
        f[j * 8 + e * 2] += __uint_as_float(uu[e] << 16);
        f[j * 8 + e * 2 + 1] += __uint_as_float(uu[e] & 0xffff0000u);
      }
    }
  }
}

static __device__ inline void load48_f32(const float* __restrict__ A, int row,
                                         int lane, float* f) {
  const float4* r0 = (const float4*)(A + (size_t)row * NN);
#pragma unroll
  for (int j = 0; j < 12; ++j) {
    float4 a = r0[lane + j * 64];
    f[j * 4 + 0] = a.x; f[j * 4 + 1] = a.y;
    f[j * 4 + 2] = a.z; f[j * 4 + 3] = a.w;
  }
}

// ---------------------------------------------------------------------------
// select top-64 of the wave's 64x48 values (radix on bits [30..16], OR/AND
// prefix-skip), compact (idx,val*descale) into out arrays (128 slots; LDS or
// global). bf selects the column-index mapping of the loader used.
static __device__ void select_compact(const float* f, int lane, float descale,
                                      int bf, int* __restrict__ outCnt,
                                      int* __restrict__ outIdx,
                                      float* __restrict__ outVal) {
  unsigned bor = 0, band = 0xffffffffu;
#pragma unroll
  for (int r = 0; r < 48; ++r) {
    unsigned k = __float_as_uint(f[r]);
    bor |= k; band &= k;
  }
  for (int off = 32; off; off >>= 1) {
    bor |= (unsigned)__shfl_down((int)bor, off, 64);
    band &= (unsigned)__shfl_down((int)band, off, 64);
  }
  bor = (unsigned)__shfl((int)bor, 0, 64);
  band = (unsigned)__shfl((int)band, 0, 64);
  unsigned diff = bor ^ band;
  int hi = diff ? (31 - __clz(diff)) : 16;
  if (hi < 16) hi = 16;
  if (hi > 30) hi = 30;
  unsigned t = band & ~((hi < 31) ? ((2u << hi) - 1u) : 0xffffffffu);

  for (int b = hi; b >= 16; --b) {
    unsigned cand = t | (1u << b);
    int c = 0;
#pragma unroll
    for (int r = 0; r < 48; ++r) c += (__float_as_uint(f[r]) >= cand) ? 1 : 0;
    for (int off = 32; off; off >>= 1) c += __shfl_down(c, off, 64);
    c = __shfl(c, 0, 64);
    if (c >= 64) t = cand;
  }
  int basec = 0;
#pragma unroll
  for (int r = 0; r < 48; ++r) {
    bool keep = __float_as_uint(f[r]) >= t;
    unsigned long long m = __ballot(keep);
    if (keep) {
      int pos = basec + __popcll(m & ((1ull << lane) - 1ull));
      if (pos < 128) {
        outIdx[pos] = bf ? ((r >> 3) * 512 + lane * 8 + (r & 7))
                         : ((r >> 2) * 256 + lane * 4 + (r & 3));
        outVal[pos] = f[r] * descale;
      }
    }
    basec += __popcll(m);
  }
  if (lane == 0) *outCnt = basec < 128 ? basec : 128;
}

// ---------------------------------------------------------------------------
// prep: A -> fp8 PACKED (straight + transposed, x2^19) + fused y1/s1 matvec
// partials. grid 2304 (48x48 tiles of 64x64).
__global__ __launch_bounds__(256) void prep(
    const float* __restrict__ A, const float* __restrict__ vu,
    const float* __restrict__ vv, unsigned char* __restrict__ Af8,
    unsigned char* __restrict__ Atf8, float* __restrict__ y1,
    float* __restrict__ s1) {
  __shared__ float sh[64 * 65 + 512];
  const int bid = blockIdx.x;
  const int t = threadIdx.x;
  const int bx = (bid % 48) * 64, by = (bid / 48) * 64;
  const int rr = t >> 4;
  const int c4 = (t & 15) * 4;
  for (int it = 0; it < 4; ++it) {
    int r = rr + it * 16;
    float4 val = *(const float4*)(A + (size_t)(by + r) * NN + bx + c4);
    sh[r * 65 + c4] = val.x; sh[r * 65 + c4 + 1] = val.y;
    sh[r * 65 + c4 + 2] = val.z; sh[r * 65 + c4 + 3] = val.w;
  }
  __syncthreads();
  {
    int row = t >> 2, ch = t & 3;
    const float* sp = &sh[row * 65 + ch * 16];
    uint4 w;
    w.x = pk4_f8(sp[0] * SCALE_A, sp[1] * SCALE_A, sp[2] * SCALE_A,
                 sp[3] * SCALE_A);
    w.y = pk4_f8(sp[4] * SCALE_A, sp[5] * SCALE_A, sp[6] * SCALE_A,
                 sp[7] * SCALE_A);
    w.z = pk4_f8(sp[8] * SCALE_A, sp[9] * SCALE_A, sp[10] * SCALE_A,
                 sp[11] * SCALE_A);
    w.w = pk4_f8(sp[12] * SCALE_A, sp[13] * SCALE_A, sp[14] * SCALE_A,
                 sp[15] * SCALE_A);
    *(uint4*)(Af8 + (size_t)(bx >> 6) * KBLK + (size_t)(by + row) * 64 +
              ch * 16) = w;
  }
  {
    int c = t >> 2, ch = t & 3;
    float v[16];
#pragma unroll
    for (int e = 0; e < 16; ++e) v[e] = sh[(ch * 16 + e) * 65 + c];
    uint4 w;
    w.x = pk4_f8(v[0] * SCALE_A, v[1] * SCALE_A, v[2] * SCALE_A,
                 v[3] * SCALE_A);
    w.y = pk4_f8(v[4] * SCALE_A, v[5] * SCALE_A, v[6] * SCALE_A,
                 v[7] * SCALE_A);
    w.z = pk4_f8(v[8] * SCALE_A, v[9] * SCALE_A, v[10] * SCALE_A,
                 v[11] * SCALE_A);
    w.w = pk4_f8(v[12] * SCALE_A, v[13] * SCALE_A, v[14] * SCALE_A,
                 v[15] * SCALE_A);
    *(uint4*)(Atf8 + (size_t)(by >> 6) * KBLK + (size_t)(bx + c) * 64 +
              ch * 16) = w;
  }
  const int q = t >> 6;
  const int l = t & 63;
  float sy = 0.f, ss_ = 0.f;
  for (int i = 0; i < 16; ++i) {
    int c = q * 16 + i;
    sy += sh[l * 65 + c] * vv[bx + c];
    ss_ += vu[by + c] * sh[c * 65 + l];
  }
  float* red = sh + 64 * 65;
  red[q * 64 + l] = sy;
  red[256 + q * 64 + l] = ss_;
  __syncthreads();
  if (t < 64) {
    float v4 = red[t] + red[64 + t] + red[128 + t] + red[192 + t];
    atomAddF(&y1[by + t], v4);
  } else if (t < 128) {
    int cc = t - 64;
    float v4 = red[256 + cc] + red[256 + 64 + cc] + red[256 + 128 + cc] +
               red[256 + 192 + cc];
    atomAddF(&s1[bx + cc], v4);
  }
}

// ---------------------------------------------------------------------------
// LDS-free fp8 GEMM via MX-scaled 32x32x64 MFMA at unit scales. Register
// double-buffered; no barriers in the K-loop.
static __device__ inline i32x8 ldfrag(const unsigned char* p) {
  i32x4 lo = *(const i32x4*)p;
  i32x4 hi = *(const i32x4*)(p + 16);
  return (i32x8){lo.x, lo.y, lo.z, lo.w, hi.x, hi.y, hi.z, hi.w};
}

__global__ __launch_bounds__(256) void gemm_f8(
    const unsigned char* __restrict__ Ag,
    const unsigned char* __restrict__ Btg,
    unsigned short* __restrict__ Cg, int kLen) {
  const int tid = threadIdx.x;
  const int wave = tid >> 6;
  const int lane = tid & 63;
  const int rowBase = blockIdx.y * 128;
  const int colBase = blockIdx.x * 128;
  const int wr = wave >> 1, wc = wave & 1;
  const int r32 = lane & 31, hh = lane >> 5;
  const int kStart = blockIdx.z * kLen;
  unsigned short* Cout = Cg + (size_t)blockIdx.z * NN * NN;

  f32x16 acc[2][2];
  for (int i = 0; i < 2; ++i)
    for (int j = 0; j < 2; ++j)
      for (int e = 0; e < 16; ++e) acc[i][j][e] = 0.f;

  const unsigned char* aP0 = Ag + (size_t)(kStart >> 6) * KBLK +
                             (size_t)(rowBase + (wr * 2) * 32 + r32) * 64 +
                             hh * 32;
  const unsigned char* aP1 = aP0 + 32 * 64;
  const unsigned char* bP0 = Btg + (size_t)(kStart >> 6) * KBLK +
                             (size_t)(colBase + (wc * 2) * 32 + r32) * 64 +
                             hh * 32;
  const unsigned char* bP1 = bP0 + 32 * 64;

  const int nIter = kLen >> 6;
  i32x8 a0 = ldfrag(aP0), a1 = ldfrag(aP1);
  i32x8 b0 = ldfrag(bP0), b1 = ldfrag(bP1);
  for (int it = 0; it < nIter - 1; ++it) {
    aP0 += KBLK; aP1 += KBLK; bP0 += KBLK; bP1 += KBLK;
    i32x8 na0 = ldfrag(aP0), na1 = ldfrag(aP1);
    i32x8 nb0 = ldfrag(bP0), nb1 = ldfrag(bP1);
    acc[0][0] = __builtin_amdgcn_mfma_scale_f32_32x32x64_f8f6f4(
        a0, b0, acc[0][0], 0, 0, 0, 127, 0, 127);
    acc[0][1] = __builtin_amdgcn_mfma_scale_f32_32x32x64_f8f6f4(
        a0, b1, acc[0][1], 0, 0, 0, 127, 0, 127);
    acc[1][0] = __builtin_amdgcn_mfma_scale_f32_32x32x64_f8f6f4(
        a1, b0, acc[1][0], 0, 0, 0, 127, 0, 127);
    acc[1][1] = __builtin_amdgcn_mfma_scale_f32_32x32x64_f8f6f4(
        a1, b1, acc[1][1], 0, 0, 0, 127, 0, 127);
    a0 = na0; a1 = na1; b0 = nb0; b1 = nb1;
  }
  acc[0][0] = __builtin_amdgcn_mfma_scale_f32_32x32x64_f8f6f4(
      a0, b0, acc[0][0], 0, 0, 0, 127, 0, 127);
  acc[0][1] = __builtin_amdgcn_mfma_scale_f32_32x32x64_f8f6f4(
      a0, b1, acc[0][1], 0, 0, 0, 127, 0, 127);
  acc[1][0] = __builtin_amdgcn_mfma_scale_f32_32x32x64_f8f6f4(
      a1, b0, acc[1][0], 0, 0, 0, 127, 0, 127);
  acc[1][1] = __builtin_amdgcn_mfma_scale_f32_32x32x64_f8f6f4(
      a1, b1, acc[1][1], 0, 0, 0, 127, 0, 127);

  // C/D 32x32 layout: col = lane&31, row = (reg&3) + 8*(reg>>2) + 4*(lane>>5)
  for (int i = 0; i < 2; ++i) {
    int rb = rowBase + wr * 64 + i * 32 + 4 * hh;
    for (int j = 0; j < 2; ++j) {
      int cc = colBase + wc * 64 + j * 32 + r32;
      for (int reg = 0; reg < 16; ++reg) {
        int rr = rb + (reg & 3) + 8 * (reg >> 2);
        Cout[(size_t)rr * NN + cc] = bf16bits(acc[i][j][reg]);
      }
    }
  }
}

// ---------------------------------------------------------------------------
// post1: [0,768)    topk(A2 bf16 partial-sum) + packed fp8 cast -> A2f8
//        [768,1536) tvec = A.y1 (one wave per row)
__global__ __launch_bounds__(256) void post1(
    const unsigned short* __restrict__ C, int parts,
    const float* __restrict__ A, const float* __restrict__ y1,
    unsigned char* __restrict__ A2f8, int* __restrict__ cnts1,
    int* __restrict__ tIdx1, float* __restrict__ tVal1,
    float* __restrict__ tvec) {
  const int bid = blockIdx.x;
  const int t = threadIdx.x;
  if (bid < 768) {
    int row = bid * 4 + (t >> 6);
    int lane = t & 63;
    float f[48];
    load48_bf(C, parts, row, lane, f);
    // fused packed fp8 cast: f[j*8+e] = col k0+e, k0=(j*64+lane)*8
#pragma unroll
    for (int j = 0; j < 6; ++j) {
      uint2 w;
      w.x = pk4_f8(f[j * 8 + 0] * F8SCALE2, f[j * 8 + 1] * F8SCALE2,
                   f[j * 8 + 2] * F8SCALE2, f[j * 8 + 3] * F8SCALE2);
      w.y = pk4_f8(f[j * 8 + 4] * F8SCALE2, f[j * 8 + 5] * F8SCALE2,
                   f[j * 8 + 6] * F8SCALE2, f[j * 8 + 7] * F8SCALE2);
      size_t addr = (size_t)(j * 8 + (lane >> 3)) * KBLK +
                    (size_t)row * 64 + (lane & 7) * 8;
      *(uint2*)(A2f8 + addr) = w;
    }
    select_compact(f, lane, DESCALE38, 1, &cnts1[row],
                   tIdx1 + (size_t)row * 128, tVal1 + (size_t)row * 128);
  } else {
    int row = (bid - 768) * 4 + (t >> 6);
    int lane = t & 63;
    const float4* rp = (const float4*)(A + (size_t)row * NN);
    const float4* yp = (const float4*)y1;
    float s = 0.f;
#pragma unroll
    for (int j = 0; j < 12; ++j) {
      float4 a = rp[lane + j * 64];
      float4 y = yp[lane + j * 64];
      s += a.x * y.x + a.y * y.y + a.z * y.z + a.w * y.w;
    }
    for (int off = 32; off; off >>= 1) s += __shfl_down(s, off, 64);
    if (lane == 0) tvec[row] = s;
  }
}

// ---------------------------------------------------------------------------
// post2: single block -> w0..w3
__global__ __launch_bounds__(256) void post2(
    const float* __restrict__ vu, const float* __restrict__ vv,
    const float* __restrict__ y1, const float* __restrict__ s1,
    const float* __restrict__ tvec, float* __restrict__ wacc) {
  __shared__ float red4[4];
  const int t = threadIdx.x;
  float w0 = row_dot_f32(vu, vv, red4);  __syncthreads();
  float w1 = row_dot_f32(vu, y1, red4);  __syncthreads();
  float w2 = row_dot_f32(s1, y1, red4);  __syncthreads();
  float w3 = row_dot_f32(s1, tvec, red4);
  if (t == 0) { wacc[0] = w0; wacc[1] = w1; wacc[2] = w2; wacc[3] = w3; }
}

// ---------------------------------------------------------------------------
static __device__ inline float ldE(const float* __restrict__ ue,
                                   const float* __restrict__ ie, int r, int d) {
  return r < NU ? ue[(size_t)r * DD + d] : ie[(size_t)(r - NU) * DD + d];
}

// build_light with FUSED row-local topk: wave0 selects layer 2 (A3 from bf16
// partials), wave1 selects layer 0 (A fp32); both land in LDS (no global
// round-trip). Layer 1 read from post1's global arrays.
__global__ __launch_bounds__(128) void build_light(
    const unsigned short* __restrict__ C, int parts,
    const float* __restrict__ A, const float* __restrict__ uemb,
    const float* __restrict__ iemb, const float* __restrict__ uemb0,
    const float* __restrict__ iemb0, const float* __restrict__ wacc,
    const int* __restrict__ cnts1, const int* __restrict__ tIdx1,
    const float* __restrict__ tVal1, float* __restrict__ lightOut) {
  __shared__ int l0i[128];
  __shared__ float l0v[128];
  __shared__ int l2i[128];
  __shared__ float l2v[128];
  __shared__ int lcnt[2];  // [0]=layer0, [1]=layer2
  __shared__ int s1i[128];
  __shared__ float s1v[128];

  const int row = blockIdx.x;
  const int t = threadIdx.x;
  const int lane = t & 63;
  {
    float f[48];
    if (t < 64) {
      load48_bf(C, parts, row, lane, f);
      select_compact(f, lane, DESCALE38, 1, &lcnt[1], l2i, l2v);
    } else {
      load48_f32(A, row, lane, f);
      select_compact(f, lane, 1.0f, 0, &lcnt[0], l0i, l0v);
    }
  }
  __syncthreads();

  float w0 = wacc[0], w1 = wacc[1], w2 = wacc[2], w3 = wacc[3];
  float ss = w0 + w1 + w2 + w3;
  w0 /= ss; w1 /= ss; w2 /= ss; w3 /= ss;
  float m = fmaxf(fmaxf(w0, w1), fmaxf(w2, w3));
  float e0 = expf(w0 - m), e1 = expf(w1 - m), e2 = expf(w2 - m),
        e3 = expf(w3 - m);
  float se = e0 + e1 + e2 + e3;
  float aw0 = e0 / se, aw1 = e1 / se, aw2 = e2 / se, aw3 = e3 / se;
  float aw4 = GAMMA_F * (aw1 + aw2 + aw3);

  const int d = t;
  float acc = aw0 * ldE(uemb, iemb, row, d) + aw4 * ldE(uemb0, iemb0, row, d);

  // layer 0 (from LDS)
  {
    int c = lcnt[0];
    float la = 0.f;
    for (int k = 0; k < c; ++k) la += l0v[k] * ldE(uemb, iemb, l0i[k], d);
    acc += aw1 * la;
  }
  // layer 1 (stage global -> LDS)
  int c1 = cnts1[row];
  if (d < c1) {
    s1i[d] = tIdx1[(size_t)row * 128 + d];
    s1v[d] = tVal1[(size_t)row * 128 + d];
  }
  __syncthreads();
  {
    float la = 0.f;
    for (int k = 0; k < c1; ++k) la += s1v[k] * ldE(uemb, iemb, s1i[k], d);
    acc += aw2 * la;
  }
  // layer 2 (from LDS)
  {
    int c = lcnt[1];
    float la = 0.f;
    for (int k = 0; k < c; ++k) la += l2v[k] * ldE(uemb, iemb, l2i[k], d);
    acc += aw3 * la;
  }
  lightOut[(size_t)row * DD + d] = acc;
}

__global__ __launch_bounds__(256) void out_dot(const int* __restrict__ users,
                                               const int* __restrict__ items,
                                               const float* __restrict__ lightOut,
                                               float* __restrict__ out) {
  int b = blockIdx.x * 4 + (threadIdx.x >> 6);
  int lane = threadIdx.x & 63;
  const float* up = lightOut + (size_t)users[b] * DD;
  const float* ip = lightOut + (size_t)(NU + items[b]) * DD;
  float s = up[lane] * ip[lane] + up[lane + 64] * ip[lane + 64];
  for (int off = 32; off; off >>= 1) s += __shfl_down(s, off, 64);
  if (lane == 0) out[b] = s;
}

// ---------------------------------------------------------------------------
extern "C" void kernel_launch(void* const* d_in, const int* in_sizes, int n_in,
                              void* d_out, int out_size, void* d_ws,
                              size_t ws_size, hipStream_t stream) {
  const int* users = (const int*)d_in[0];
  const int* items = (const int*)d_in[1];
  const float* A = (const float*)d_in[2];
  const float* uemb = (const float*)d_in[3];
  const float* iemb = (const float*)d_in[4];
  const float* uemb0 = (const float*)d_in[5];
  const float* iemb0 = (const float*)d_in[6];
  const float* vu = (const float*)d_in[7];
  const float* vv = (const float*)d_in[8];
  float* out = (float*)d_out;

  char* ws = (char*)d_ws;
  size_t off = 0;
  auto alloc = [&](size_t bytes) -> void* {
    void* p = ws + off;
    off += (bytes + 255) & ~(size_t)255;
    return p;
  };
  unsigned char* Af8 = (unsigned char*)alloc((size_t)NN * NN);
  unsigned char* Atf8 = (unsigned char*)alloc((size_t)NN * NN);
  unsigned char* A2f8 = (unsigned char*)alloc((size_t)NN * NN);
  float* y1 = (float*)alloc((size_t)NN * 4);   // contiguous with s1
  float* s1 = (float*)alloc((size_t)NN * 4);
  float* tvec = (float*)alloc((size_t)NN * 4);
  float* wacc = (float*)alloc(256);
  int* cnts1 = (int*)alloc((size_t)NN * 4);
  int* tIdx1 = (int*)alloc((size_t)NN * 128 * 4);
  float* tVal1 = (float*)alloc((size_t)NN * 128 * 4);
  float* lightOut = (float*)alloc((size_t)NN * DD * 4);

  const size_t cBytes = (size_t)NN * NN * 2;  // bf16 partials
  int kParts = (ws_size >= off + 2 * cBytes + 512) ? 2 : 1;
  unsigned short* C = (unsigned short*)alloc((size_t)kParts * cBytes);
  const int kLen = NN / kParts;

  // 1) zero y1/s1 (contiguous 2*NN floats)
  hipMemsetAsync(y1, 0, (size_t)2 * NN * 4, stream);
  // 2) prep: A -> packed fp8 (straight+transposed) + y1/s1 partials
  prep<<<2304, 256, 0, stream>>>(A, vu, vv, Af8, Atf8, y1, s1);
  // 3) A2 = A*A (LDS-free MX fp8 MFMA, bf16 partials x2)
  gemm_f8<<<dim3(24, 24, kParts), 256, 0, stream>>>(Af8, Atf8, C, kLen);
  // 4) post1: topk(A2)+packed fp8 cast | tvec = A.y1
  post1<<<1536, 256, 0, stream>>>(C, kParts, A, y1, A2f8, cnts1, tIdx1,
                                  tVal1, tvec);
  // 5) A3 = A2*A (overwrite partials)
  gemm_f8<<<dim3(24, 24, kParts), 256, 0, stream>>>(A2f8, Atf8, C, kLen);
  // 6) post2: w0..w3 (single block)
  post2<<<1, 256, 0, stream>>>(vu, vv, y1, s1, tvec, wacc);
  // 7) build_light with fused row-local topk(A) and topk(A3)
  build_light<<<NN, 128, 0, stream>>>(C, kParts, A, uemb, iemb, uemb0, iemb0,
                                      wacc, cnts1, tIdx1, tVal1, lightOut);
  // 8) gather dots
  out_dot<<<BB / 4, 256, 0, stream>>>(users, items, lightOut, out);
}